// Round 4
// baseline (686.815 us; speedup 1.0000x reference)
//
#include <hip/hip_runtime.h>
#include <math.h>

#define Bb 32
#define Nn 2048
#define Dd 512
#define NS 8
#define ITERS 3
#define EPSf 1e-8f
#define SCALEf 0.04419417382415922f   // 512^-0.5
#define LN_EPSf 1e-5f

#define QHS 520    // qh LDS row stride (halves)
#define PTS 136    // pT LDS row stride (halves)
#define CHUNKS 16  // attention token chunks (128 tokens each)

typedef _Float16 half8 __attribute__((ext_vector_type(8)));
typedef float f32x4 __attribute__((ext_vector_type(4)));

__device__ __forceinline__ float waveReduceSum(float v) {
    #pragma unroll
    for (int m = 32; m >= 1; m >>= 1) v += __shfl_xor(v, m);
    return v;
}

__device__ __forceinline__ float gelu_exact(float x) {
    return 0.5f * x * (1.0f + erff(x * 0.7071067811865476f));
}

__device__ __forceinline__ void async_copy16(const _Float16* g, _Float16* l) {
    __builtin_amdgcn_global_load_lds(
        (const __attribute__((address_space(1))) unsigned int*)g,
        (__attribute__((address_space(3))) unsigned int*)l, 16, 0, 0);
}

// ================= pack kernels =================
__global__ __launch_bounds__(256) void megapack_kernel(
    const float* __restrict__ k_w, const float* __restrict__ v_w,
    const float* __restrict__ w_ih, const float* __restrict__ w_hh,
    const float* __restrict__ m1, const float* __restrict__ m2,
    const float* __restrict__ m3, const float* __restrict__ m4,
    _Float16* __restrict__ Bkv, _Float16* __restrict__ Bih, _Float16* __restrict__ Bhh,
    _Float16* __restrict__ Bm1, _Float16* __restrict__ Bm2,
    _Float16* __restrict__ Bm3, _Float16* __restrict__ Bm4) {
    int bid = blockIdx.x, tid = threadIdx.x;
    const float* src; _Float16* dst; int kbits, base;
    if (bid < 2048) {   // kv plain copy
        int i = bid * 256 + tid;
        Bkv[i] = (_Float16)(i < 262144 ? k_w[i] : v_w[i - 262144]);
        return;
    }
    else if (bid < 5120)  { src = w_ih; dst = Bih; kbits = 9;  base = 2048; }
    else if (bid < 8192)  { src = w_hh; dst = Bhh; kbits = 9;  base = 5120; }
    else if (bid < 10240) { src = m1;   dst = Bm1; kbits = 9;  base = 8192; }
    else if (bid < 14336) { src = m2;   dst = Bm2; kbits = 10; base = 10240; }
    else if (bid < 16384) { src = m3;   dst = Bm3; kbits = 10; base = 14336; }
    else                  { src = m4;   dst = Bm4; kbits = 9;  base = 16384; }
    int e = (bid - base) * 256 + tid;
    int K = 1 << kbits;
    int row = e >> kbits, k = e & (K - 1);
    _Float16 h = (_Float16)src[e];
    _Float16* d = dst + ((size_t)row << (kbits + 1));
    d[k] = h;
    d[K + k] = h;
}

// LN(inputs) -> Apack fp16 [65536][512]
__global__ __launch_bounds__(256) void pack_ln_single_kernel(
    const float* __restrict__ x, const float* __restrict__ g, const float* __restrict__ b,
    _Float16* __restrict__ Ap) {
    int wid = blockIdx.x * 4 + (threadIdx.x >> 6);
    int lane = threadIdx.x & 63;
    const float4* row4 = (const float4*)(x + (size_t)wid * Dd);
    float4 va = row4[lane * 2], vb = row4[lane * 2 + 1];
    float v[8] = {va.x, va.y, va.z, va.w, vb.x, vb.y, vb.z, vb.w};
    float s = 0.f, sq = 0.f;
    #pragma unroll
    for (int t = 0; t < 8; ++t) { s += v[t]; sq += v[t] * v[t]; }
    s = waveReduceSum(s);
    sq = waveReduceSum(sq);
    float m = s * (1.0f / Dd);
    float var = sq * (1.0f / Dd) - m * m;
    float rs = rsqrtf(var + LN_EPSf);
    const float4* g4 = (const float4*)g;
    const float4* b4 = (const float4*)b;
    float4 ga = g4[lane * 2], gb = g4[lane * 2 + 1];
    float4 ba = b4[lane * 2], bb = b4[lane * 2 + 1];
    float gg[8] = {ga.x, ga.y, ga.z, ga.w, gb.x, gb.y, gb.z, gb.w};
    float bbv[8] = {ba.x, ba.y, ba.z, ba.w, bb.x, bb.y, bb.z, bb.w};
    half8 o;
    #pragma unroll
    for (int t = 0; t < 8; ++t) o[t] = (_Float16)((v[t] - m) * rs * gg[t] + bbv[t]);
    *(half8*)(Ap + (size_t)wid * Dd + lane * 8) = o;
}

// slots init, wave-per-row: slots fp32, A2 slot-rows (hi|lo), qh = LN(slots)*scale fp16
__global__ __launch_bounds__(256) void slots_init_kernel(
    const float* __restrict__ noise, const float* __restrict__ mu,
    const float* __restrict__ ls, float* __restrict__ slots, _Float16* __restrict__ A2,
    const float* __restrict__ lns_g, const float* __restrict__ lns_b,
    _Float16* __restrict__ qh) {
    int row = blockIdx.x * 4 + (threadIdx.x >> 6);
    int lane = threadIdx.x & 63;
    float val[8];
    float s = 0.f, sq = 0.f;
    #pragma unroll
    for (int t = 0; t < 8; ++t) {
        int d = t * 64 + lane;
        float v = mu[d] + expf(ls[d]) * noise[(size_t)row * 512 + d];
        val[t] = v;
        s += v; sq += v * v;
        slots[(size_t)row * 512 + d] = v;
        _Float16 hi = (_Float16)v;
        A2[(size_t)(256 + row) * 1024 + d] = hi;
        A2[(size_t)(256 + row) * 1024 + 512 + d] = (_Float16)(v - (float)hi);
    }
    s = waveReduceSum(s);
    sq = waveReduceSum(sq);
    float m = s * (1.0f / Dd);
    float var = sq * (1.0f / Dd) - m * m;
    float rs = rsqrtf(var + LN_EPSf);
    #pragma unroll
    for (int t = 0; t < 8; ++t) {
        int d = t * 64 + lane;
        qh[(size_t)row * 512 + d] = (_Float16)(((val[t] - m) * rs * lns_g[d] + lns_b[d]) * SCALEf);
    }
}

// ================= kv projection: 256x256 tile, frag-pipelined counted-vmcnt =================
// M=65536, N=1024, K=512. BK=64, 8 K-tiles x 2 kk-phases = 16 phases.
// 8 waves (2m x 4n), per-wave 128x64 out. LDS dbuf 128 KB, st-16B XOR swizzle.
// FRAGMENT PIPELINE (m201/T3+T4): each phase issues the NEXT phase's 12 ds_read_b128
// BEFORE its own 32 MFMA; lgkmcnt(12) (counted, not 0) retires only the PREVIOUS
// phase's reads -> LDS drain (~1150 cyc/CU) overlaps the MFMA region (~1240 cyc/SIMD).
// ONE barrier per phase: reads issue pre-barrier, stage DMAs post-barrier, so every
// ds_read of a region is block-wide ordered before the DMA that overwrites it
// (DMA lands >=900 cyc after issue vs <=300 cyc read drain).
// DMA ledger (4/phase/wave): A(t+2) issued at (t,0), B(t+2) at (t,1), both into the
// CURRENT-parity buffer (regions dead after this phase's reads). Waits: vmcnt(4) at
// (t,1) start guarantees tile t+1 resident before its kk=0 frag reads. Never vmcnt(0)
// in the loop. Prologue: 16 DMAs, vmcnt(8) = tile 0 resident.

__global__ __launch_bounds__(512, 2) void kv_hgemm256_kernel(
    const _Float16* __restrict__ Apack, const _Float16* __restrict__ Bkv,
    const float* __restrict__ k_b, const float* __restrict__ v_b,
    _Float16* __restrict__ khalf, _Float16* __restrict__ vT) {
    __shared__ _Float16 lds[4][16384];   // [parity*2 + (0=A,1=B)][256 rows x 64 halves]
    const int f = blockIdx.x;
    const int swz = ((f & 7) << 7) + (f >> 3);     // 1024 % 8 == 0: bijective XCD swizzle
    const int m0 = (swz >> 2) << 8;
    const int n0 = (swz & 3) << 8;
    const int tid = threadIdx.x;
    const int lane = tid & 63;
    const int wid = tid >> 6;
    const int lr = lane & 15, quad = lane >> 4;
    const int wm = wid >> 2, wn = wid & 3;
    // staging geometry: global source column pre-swizzled so linear LDS dest ends up
    // XOR-swizzled (both-sides-or-neither, rule 21).
    const int grow = tid >> 3;                                  // 0..63
    const int sslot = ((tid & 7) ^ (grow & 7)) << 3;            // halves
    const int lwave = wid << 9;                                 // wid*512 halves = 1 KB

    f32x4 acc[8][4];
    #pragma unroll
    for (int i = 0; i < 8; ++i)
        #pragma unroll
        for (int j = 0; j < 4; ++j) acc[i][j] = (f32x4){0.f, 0.f, 0.f, 0.f};

    auto stageA = [&](int ktile, int par, int g) {
        const _Float16* src = Apack + (size_t)(m0 + (g << 6) + grow) * 512 +
                              ((ktile & 7) << 6) + sslot;
        async_copy16(src, &lds[par * 2][(g << 12) + lwave]);
    };
    auto stageB = [&](int ktile, int par, int g) {
        const _Float16* src = Bkv + (size_t)(n0 + (g << 6) + grow) * 512 +
                              ((ktile & 7) << 6) + sslot;
        async_copy16(src, &lds[par * 2 + 1][(g << 12) + lwave]);
    };
    auto readFA = [&](const _Float16* Asrc, int kk, half8* fa) {
        #pragma unroll
        for (int mt = 0; mt < 8; ++mt) {
            int R = wm * 128 + mt * 16 + lr;
            fa[mt] = *(const half8*)(Asrc + R * 64 +
                     ((((kk << 2) | quad) ^ (lr & 7)) << 3));
        }
    };
    auto readFB = [&](const _Float16* Bsrc, int kk, half8* fb) {
        #pragma unroll
        for (int nt = 0; nt < 4; ++nt) {
            int R = wn * 64 + nt * 16 + lr;
            fb[nt] = *(const half8*)(Bsrc + R * 64 +
                     ((((kk << 2) | quad) ^ (lr & 7)) << 3));
        }
    };

    // prologue: tiles 0,1 staged (FIFO: A0 B0 A1 B1); vmcnt(8) = tile 0 resident
    stageA(0, 0, 0); stageA(0, 0, 1); stageA(0, 0, 2); stageA(0, 0, 3);
    stageB(0, 0, 0); stageB(0, 0, 1); stageB(0, 0, 2); stageB(0, 0, 3);
    stageA(1, 1, 0); stageA(1, 1, 1); stageA(1, 1, 2); stageA(1, 1, 3);
    stageB(1, 1, 0); stageB(1, 1, 1); stageB(1, 1, 2); stageB(1, 1, 3);
    asm volatile("s_waitcnt vmcnt(8)" ::: "memory");
    __builtin_amdgcn_s_barrier();

    half8 fa0[8], fb0[4], fa1[8], fb1[4];
    readFA(&lds[0][0], 0, fa0);          // frags (tile 0, kk=0)
    readFB(&lds[1][0], 0, fb0);

    #pragma unroll 2
    for (int t = 0; t < 8; ++t) {
        const int cur = t & 1, nxt = cur ^ 1;
        const _Float16* AldsC = &lds[cur * 2][0];
        const _Float16* BldsC = &lds[cur * 2 + 1][0];
        const _Float16* AldsN = &lds[nxt * 2][0];
        const _Float16* BldsN = &lds[nxt * 2 + 1][0];

        // ---- phase (t,0): read (t,kk=1) frags; stage A(t+2); MFMA kk=0 ----
        readFA(AldsC, 1, fa1);
        readFB(BldsC, 1, fb1);
        __builtin_amdgcn_s_barrier();
        stageA(t + 2, cur, 0); stageA(t + 2, cur, 1);
        stageA(t + 2, cur, 2); stageA(t + 2, cur, 3);
        asm volatile("s_waitcnt lgkmcnt(12)" ::: "memory");
        __builtin_amdgcn_sched_barrier(0);
        __builtin_amdgcn_s_setprio(1);
        #pragma unroll
        for (int mt = 0; mt < 8; ++mt)
            #pragma unroll
            for (int nt = 0; nt < 4; ++nt)
                acc[mt][nt] = __builtin_amdgcn_mfma_f32_16x16x32_f16(
                    fa0[mt], fb0[nt], acc[mt][nt], 0, 0, 0);
        __builtin_amdgcn_s_setprio(0);

        // ---- phase (t,1): tile t+1 resident check; read (t+1,kk=0); stage B(t+2);
        //      MFMA kk=1 ----
        asm volatile("s_waitcnt vmcnt(4)" ::: "memory");
        readFA(AldsN, 0, fa0);
        readFB(BldsN, 0, fb0);
        __builtin_amdgcn_s_barrier();
        stageB(t + 2, cur, 0); stageB(t + 2, cur, 1);
        stageB(t + 2, cur, 2); stageB(t + 2, cur, 3);
        asm volatile("s_waitcnt lgkmcnt(12)" ::: "memory");
        __builtin_amdgcn_sched_barrier(0);
        __builtin_amdgcn_s_setprio(1);
        #pragma unroll
        for (int mt = 0; mt < 8; ++mt)
            #pragma unroll
            for (int nt = 0; nt < 4; ++nt)
                acc[mt][nt] = __builtin_amdgcn_mfma_f32_16x16x32_f16(
                    fa1[mt], fb1[nt], acc[mt][nt], 0, 0, 0);
        __builtin_amdgcn_s_setprio(0);
    }

    // drain tail DMA (wrapped garbage stages still in flight) before reusing LDS
    asm volatile("s_waitcnt vmcnt(0)" ::: "memory");
    __builtin_amdgcn_s_barrier();

    // ---- epilogue: stage C through LDS (XOR-swizzled), coalesced half8 stores ----
    _Float16* Cs = &lds[0][0];
    const bool isK = (n0 < 512);
    #pragma unroll
    for (int mt = 0; mt < 8; ++mt)
        #pragma unroll
        for (int nt = 0; nt < 4; ++nt) {
            int n = wn * 64 + nt * 16 + lr;
            float bv = isK ? k_b[n0 + n] : v_b[n0 - 512 + n];
            #pragma unroll
            for (int r = 0; r < 4; ++r) {
                int m = wm * 128 + mt * 16 + quad * 4 + r;
                float val = acc[mt][nt][r] + bv;
                int row = isK ? m : n;     // K: [token][feat]; V: [feat][token]
                int col = isK ? n : m;
                int byt = (row << 9) + ((col << 1) ^ ((row & 7) << 4));
                *(_Float16*)((char*)Cs + byt) = (_Float16)val;
            }
        }
    asm volatile("s_waitcnt lgkmcnt(0)" ::: "memory");
    __builtin_amdgcn_s_barrier();

    const int rr = (wid << 1) + (lane >> 5);   // 0..15 (2 rows per wave per pass)
    const int sl = lane & 31;                  // 16B slot within 512B row
    if (isK) {
        _Float16* dst0 = khalf + (size_t)m0 * 512 + n0;
        #pragma unroll
        for (int p = 0; p < 16; ++p) {
            int row = p * 16 + rr;
            int byt = (row << 9) + (((sl ^ (row & 7)) & 31) << 4);
            *(half8*)(dst0 + (size_t)row * 512 + sl * 8) = *(const half8*)((char*)Cs + byt);
        }
    } else {
        int b = m0 >> 11, j0 = m0 & 2047, d0 = n0 - 512;
        _Float16* dst0 = vT + ((size_t)b * 512 + d0) * 2048 + j0;
        #pragma unroll
        for (int p = 0; p < 16; ++p) {
            int row = p * 16 + rr;
            int byt = (row << 9) + (((sl ^ (row & 7)) & 31) << 4);
            *(half8*)(dst0 + (size_t)row * 2048 + sl * 8) = *(const half8*)((char*)Cs + byt);
        }
    }
}

// ================= fused attention iteration (R3 shape, qh from global) =================
__global__ __launch_bounds__(256) void attn_kernel(
    const _Float16* __restrict__ qh_g,
    const _Float16* __restrict__ khalf, const _Float16* __restrict__ vT,
    float* __restrict__ rawp, float* __restrict__ sumsp) {
    const int b = blockIdx.y, chunk = blockIdx.x;
    __shared__ _Float16 qh[16 * QHS];
    __shared__ _Float16 pT[16 * PTS];
    __shared__ float sums_lds[64];
    const int tid = threadIdx.x, w = tid >> 6, lane = tid & 63;
    const int lr = lane & 15, quad = lane >> 4;

    // copy qh rows 0..7 (8 KB) from global; zero rows 8..15
    {
        int r = tid >> 5;               // 0..7
        int c = (tid & 31) * 16;        // 0..496
        *(half8*)(qh + r * QHS + c) = *(const half8*)(qh_g + ((size_t)b * NS + r) * 512 + c);
        *(half8*)(qh + r * QHS + c + 8) = *(const half8*)(qh_g + ((size_t)b * NS + r) * 512 + c + 8);
        half8 z = {};
        *(half8*)(qh + (8 + r) * QHS + c) = z;
        *(half8*)(qh + (8 + r) * QHS + c + 8) = z;
    }
    __syncthreads();

    // QK: wave handles 32 tokens; A=k rows (m=token), B=qh (n=slot)
    const int j0 = chunk * 128 + w * 32;
    f32x4 dots[2];
    dots[0] = (f32x4){0.f, 0.f, 0.f, 0.f};
    dots[1] = (f32x4){0.f, 0.f, 0.f, 0.f};
    for (int ks = 0; ks < 16; ++ks) {
        half8 bq = *(const half8*)(qh + lr * QHS + ks * 32 + quad * 8);
        #pragma unroll
        for (int mf = 0; mf < 2; ++mf) {
            half8 ak = *(const half8*)(khalf + ((size_t)b * Nn + j0 + mf * 16 + lr) * 512 + ks * 32 + quad * 8);
            dots[mf] = __builtin_amdgcn_mfma_f32_16x16x32_f16(ak, bq, dots[mf], 0, 0, 0);
        }
    }
    // softmax over slots
    float ssum = 0.f;
    #pragma unroll
    for (int mf = 0; mf < 2; ++mf) {
        f32x4 d = dots[mf];
        f32x4 mx = d;
        #pragma unroll
        for (int msk = 1; msk <= 4; msk <<= 1) {
            #pragma unroll
            for (int r = 0; r < 4; ++r) mx[r] = fmaxf(mx[r], __shfl_xor(mx[r], msk));
        }
        f32x4 p;
        #pragma unroll
        for (int r = 0; r < 4; ++r) p[r] = __expf(d[r] - mx[r]);
        f32x4 sm = p;
        #pragma unroll
        for (int msk = 1; msk <= 4; msk <<= 1) {
            #pragma unroll
            for (int r = 0; r < 4; ++r) sm[r] += __shfl_xor(sm[r], msk);
        }
        #pragma unroll
        for (int r = 0; r < 4; ++r) {
            _Float16 ph = (_Float16)(p[r] / sm[r] + EPSf);
            pT[lr * PTS + w * 32 + mf * 16 + quad * 4 + r] = ph;
            ssum += (float)ph;
        }
    }
    ssum += __shfl_xor(ssum, 16);
    ssum += __shfl_xor(ssum, 32);
    if (lane < 16) sums_lds[w * 16 + lane] = ssum;
    __syncthreads();

    // PV: A = P^T (m=slot, k=token), B = vT (n=d); wave covers d-range w*128
    f32x4 acc[8];
    #pragma unroll
    for (int nf = 0; nf < 8; ++nf) acc[nf] = (f32x4){0.f, 0.f, 0.f, 0.f};
    #pragma unroll
    for (int kc = 0; kc < 4; ++kc) {
        half8 ap = *(const half8*)(pT + lr * PTS + kc * 32 + quad * 8);
        #pragma unroll
        for (int nf = 0; nf < 8; ++nf) {
            int dcol = w * 128 + nf * 16 + lr;
            half8 bv = *(const half8*)(vT + ((size_t)b * 512 + dcol) * 2048 + chunk * 128 + kc * 32 + quad * 8);
            acc[nf] = __builtin_amdgcn_mfma_f32_16x16x32_f16(ap, bv, acc[nf], 0, 0, 0);
        }
    }
    if (quad < 2) {
        #pragma unroll
        for (int nf = 0; nf < 8; ++nf) {
            #pragma unroll
            for (int r = 0; r < 4; ++r) {
                int slot = quad * 4 + r;
                rawp[(((size_t)chunk * Bb + b) * NS + slot) * Dd + w * 128 + nf * 16 + lr] = acc[nf][r];
            }
        }
    }
    if (w == 0 && lane < NS) {
        float tot = sums_lds[lane] + sums_lds[16 + lane] + sums_lds[32 + lane] + sums_lds[48 + lane];
        sumsp[((size_t)chunk * Bb + b) * NS + lane] = tot;
    }
}

// finalize: u = sum_c rawp / sum_c sumsp ; write ubuf, out0, and A2 u-rows (hi|lo)
__global__ __launch_bounds__(256) void finalize_kernel(
    const float* __restrict__ rawp, const float* __restrict__ sumsp,
    float* __restrict__ u, float* __restrict__ out0, _Float16* __restrict__ A2) {
    int idx = blockIdx.x * 256 + threadIdx.x;   // 131072
    int row = idx >> 9, k = idx & 511;
    float rs = 0.f, ss = 0.f;
    #pragma unroll
    for (int c = 0; c < CHUNKS; ++c) {
        rs += rawp[(size_t)c * 131072 + idx];
        ss += sumsp[c * 256 + row];
    }
    float val = rs / ss;
    u[idx] = val;
    out0[idx] = val;
    _Float16 hi = (_Float16)val;
    A2[(size_t)row * 1024 + k] = hi;
    A2[(size_t)row * 1024 + 512 + k] = (_Float16)(val - (float)hi);
}

// ================= 64-tile MFMA core (small gemms, LDS-staged — R3 best) =================
__device__ __forceinline__ void hgemm64_core(
    const _Float16* __restrict__ A, const _Float16* __restrict__ Bw,
    int K2, f32x4 acc[2][2], _Float16* As, _Float16* Bs) {
    const int tid = threadIdx.x;
    const int w = tid >> 6, lane = tid & 63;
    const int r8 = lane >> 3, seg = lane & 7;
    const int lr = lane & 15, quad = lane >> 4;
    const int wm = w >> 1, wn = w & 1;
    for (int k0 = 0; k0 < K2; k0 += 64) {
        __syncthreads();
        #pragma unroll
        for (int p = 0; p < 2; ++p) {
            int grp = p * 4 + w;
            int row = grp * 8 + r8;
            async_copy16(A + (size_t)row * K2 + k0 + seg * 8, As + grp * 512);
            async_copy16(Bw + (size_t)row * K2 + k0 + seg * 8, Bs + grp * 512);
        }
        __syncthreads();
        #pragma unroll
        for (int kk = 0; kk < 2; ++kk) {
            half8 a[2], b[2];
            #pragma unroll
            for (int t = 0; t < 2; ++t) {
                a[t] = *(const half8*)(As + (wm * 32 + t * 16 + lr) * 64 + kk * 32 + quad * 8);
                b[t] = *(const half8*)(Bs + (wn * 32 + t * 16 + lr) * 64 + kk * 32 + quad * 8);
            }
            #pragma unroll
            for (int mt = 0; mt < 2; ++mt)
                #pragma unroll
                for (int nt = 0; nt < 2; ++nt)
                    acc[mt][nt] = __builtin_amdgcn_mfma_f32_16x16x32_f16(
                        a[mt], b[nt], acc[mt][nt], 0, 0, 0);
        }
    }
}

// generic 64-tile gemm: C=act(A@Bw^T+bias); PACK -> write next-layer A (hi|lo, width Kp)
template <int ACT, int PACK>
__global__ __launch_bounds__(256) void hgemm64_kernel(
    const _Float16* __restrict__ A, const _Float16* __restrict__ Bw,
    const float* __restrict__ bias, float* __restrict__ C, _Float16* __restrict__ P,
    int K2, int N, int Kp) {
    __shared__ _Float16 As[4096], Bs[4096];
    const int m0 = blockIdx.y * 64, n0 = blockIdx.x * 64;
    f32x4 acc[2][2];
    #pragma unroll
    for (int i = 0; i < 2; ++i)
        #pragma unroll
        for (int j = 0; j < 2; ++j) acc[i][j] = (f32x4){0.f, 0.f, 0.f, 0.f};
    hgemm64_core(A + (size_t)m0 * K2, Bw + (size_t)n0 * K2, K2, acc, As, Bs);
    const int tid = threadIdx.x;
    const int w = tid >> 6, lane = tid & 63;
    const int lr = lane & 15, quad = lane >> 4;
    const int wm = w >> 1, wn = w & 1;
    #pragma unroll
    for (int mt = 0; mt < 2; ++mt)
        #pragma unroll
        for (int nt = 0; nt < 2; ++nt) {
            int n = n0 + wn * 32 + nt * 16 + lr;
            float bv = bias[n];
            #pragma unroll
            for (int r = 0; r < 4; ++r) {
                int m = m0 + wm * 32 + mt * 16 + quad * 4 + r;
                float val = acc[mt][nt][r] + bv;
                if (ACT) val = gelu_exact(val);
                if (PACK) {
                    _Float16 hi = (_Float16)val;
                    P[(size_t)m * 2 * Kp + n] = hi;
                    P[(size_t)m * 2 * Kp + Kp + n] = (_Float16)(val - (float)hi);
                } else {
                    C[(size_t)m * N + n] = val;
                }
            }
        }
}

// GRU gemms: by<4 -> gi = u@w_ih^T (A2 rows 0..255), else gh = slots@w_hh^T (rows 256..511)
__global__ __launch_bounds__(256) void gru_gemm_kernel(
    const _Float16* __restrict__ A2, const _Float16* __restrict__ Bih,
    const _Float16* __restrict__ Bhh, const float* __restrict__ b_ih,
    const float* __restrict__ b_hh, float* __restrict__ gi, float* __restrict__ gh) {
    __shared__ _Float16 As[4096], Bs[4096];
    const int by = blockIdx.y;
    const int n0 = blockIdx.x * 64;
    const _Float16* Ap; const _Float16* Bw; const float* bias; float* C;
    if (by < 4) { Ap = A2 + (size_t)by * 64 * 1024;        Bw = Bih; bias = b_ih; C = gi + (size_t)by * 64 * 1536; }
    else        { Ap = A2 + (size_t)(256 + (by - 4) * 64) * 1024; Bw = Bhh; bias = b_hh; C = gh + (size_t)(by - 4) * 64 * 1536; }
    f32x4 acc[2][2];
    #pragma unroll
    for (int i = 0; i < 2; ++i)
        #pragma unroll
        for (int j = 0; j < 2; ++j) acc[i][j] = (f32x4){0.f, 0.f, 0.f, 0.f};
    hgemm64_core(Ap, Bw + (size_t)n0 * 1024, 1024, acc, As, Bs);
    const int tid = threadIdx.x;
    const int w = tid >> 6, lane = tid & 63;
    const int lr = lane & 15, quad = lane >> 4;
    const int wm = w >> 1, wn = w & 1;
    #pragma unroll
    for (int mt = 0; mt < 2; ++mt)
        #pragma unroll
        for (int nt = 0; nt < 2; ++nt) {
            int n = n0 + wn * 32 + nt * 16 + lr;
            float bv = bias[n];
            #pragma unroll
            for (int r = 0; r < 4; ++r) {
                int m = wm * 32 + mt * 16 + quad * 4 + r;
                C[(size_t)m * 1536 + n] = acc[mt][nt][r] + bv;
            }
        }
}

// GRU elementwise, wave-per-row; slots + A2 slot-rows; qh for next iter, or P1 on last
__global__ __launch_bounds__(256) void gru_elem_kernel(
    const float* __restrict__ gi, const float* __restrict__ gh,
    const float* __restrict__ u, float* __restrict__ slots, _Float16* __restrict__ A2,
    const float* __restrict__ lns_g, const float* __restrict__ lns_b,
    _Float16* __restrict__ qh,
    const float* __restrict__ lnp_g, const float* __restrict__ lnp_b,
    _Float16* __restrict__ P1, int last) {
    int row = blockIdx.x * 4 + (threadIdx.x >> 6);
    int lane = threadIdx.x & 63;
    const float* gir = gi + (size_t)row * 1536;
    const float* ghr = gh + (size_t)row * 1536;
    float val[8];
    #pragma unroll
    for (int t = 0; t < 8; ++t) {
        int d = t * 64 + lane;
        float ir = gir[d], iz = gir[512 + d], in_ = gir[1024 + d];
        float hr = ghr[d], hz = ghr[512 + d], hn = ghr[1024 + d];
        float r = 1.0f / (1.0f + expf(-(ir + hr)));
        float z = 1.0f / (1.0f + expf(-(iz + hz)));
        float n = tanhf(in_ + r * hn);
        float h = slots[(size_t)row * 512 + d];
        float hnew = (1.0f - z) * n + z * h;
        float vv = u[(size_t)row * 512 + d] + hnew;
        val[t] = vv;
        slots[(size_t)row * 512 + d] = vv;
        _Float16 hi = (_Float16)vv;
        A2[(size_t)(256 + row) * 1024 + d] = hi;
        A2[(size_t)(256 + row) * 1024 + 512 + d] = (_Float16)(vv - (float)hi);
    }
    float s = 0.f, sq = 0.f;
    #pragma unroll
    for (int t = 0; t < 8; ++t) { s += val[t]; sq += val[t] * val[t]; }
    s = waveReduceSum(s);
    sq = waveReduceSum(sq);
    float m = s * (1.0f / Dd);
    float var = sq * (1.0f / Dd) - m * m;
    float rs = rsqrtf(var + LN_EPSf);
    if (!last) {
        #pragma unroll
        for (int t = 0; t < 8; ++t) {
            int d = t * 64 + lane;
            qh[(size_t)row * 512 + d] =
                (_Float16)(((val[t] - m) * rs * lns_g[d] + lns_b[d]) * SCALEf);
        }
    } else {
        #pragma unroll
        for (int t = 0; t < 8; ++t) {
            int d = t * 64 + lane;
            float a = (val[t] - m) * rs * lnp_g[d] + lnp_b[d];
            _Float16 hi = (_Float16)a;
            P1[(size_t)row * 1024 + d] = hi;
            P1[(size_t)row * 1024 + 512 + d] = (_Float16)(a - (float)hi);
        }
    }
}

// ================= launch =================
extern "C" void kernel_launch(void* const* d_in, const int* in_sizes, int n_in,
                              void* d_out, int out_size, void* d_ws, size_t ws_size,
                              hipStream_t stream) {
    const float* inputs   = (const float*)d_in[0];
    const float* noise    = (const float*)d_in[1];
    const float* mu       = (const float*)d_in[2];
    const float* lsig     = (const float*)d_in[3];
    const float* k_w      = (const float*)d_in[4];
    const float* k_b      = (const float*)d_in[5];
    const float* v_w      = (const float*)d_in[6];
    const float* v_b      = (const float*)d_in[7];
    const float* w_ih     = (const float*)d_in[8];
    const float* w_hh     = (const float*)d_in[9];
    const float* b_ih     = (const float*)d_in[10];
    const float* b_hh     = (const float*)d_in[11];
    const float* ln_in_g  = (const float*)d_in[12];
    const float* ln_in_b  = (const float*)d_in[13];
    const float* ln_s_g   = (const float*)d_in[14];
    const float* ln_s_b   = (const float*)d_in[15];
    const float* ln_p_g   = (const float*)d_in[16];
    const float* ln_p_b   = (const float*)d_in[17];
    const float* mlp1_w   = (const float*)d_in[18];
    const float* mlp1_b   = (const float*)d_in[19];
    const float* mlp2_w   = (const float*)d_in[20];
    const float* mlp2_b   = (const float*)d_in[21];
    const float* mlp3_w   = (const float*)d_in[22];
    const float* mlp3_b   = (const float*)d_in[23];
    const float* mlp4_w   = (const float*)d_in[24];
    const float* mlp4_b   = (const float*)d_in[25];
    float* out0 = (float*)d_out;                 // updates [32,8,512]
    float* out1 = (float*)d_out + Bb * NS * Dd;  // s [32,8,256]

    char* wp = (char*)d_ws;
    auto alloc = [&](size_t bytes) -> void* {
        void* p = (void*)wp;
        wp += (bytes + 255) & ~(size_t)255;
        return p;
    };
    const size_t MR = (size_t)Bb * Nn;  // 65536
    _Float16* Apack = (_Float16*)alloc(MR * 512 * 2);           // 67 MB
    _Float16* khalf = (_Float16*)alloc(MR * 512 * 2);           // 67 MB
    _Float16* vT    = (_Float16*)alloc((size_t)Bb * 512 * Nn * 2); // 67 MB
    _Float16* Bkv   = (_Float16*)alloc((size_t)1024 * 512 * 2);
    _Float16* Bih   = (_Float16*)alloc((size_t)1536 * 1024 * 2);
    _Float16* Bhh   = (_Float16*)alloc((size_t)1536 * 1024 * 2);
    _Float16* Bm1   = (_Float16*)alloc((size_t)1024 * 1024 * 2);
    _Float16* Bm2   = (_Float16*)alloc((size_t)1024 * 2048 * 2);
    _Float16* Bm3   = (_Float16*)alloc((size_t)512 * 2048 * 2);
    _Float16* Bm4   = (_Float16*)alloc((size_t)256 * 1024 * 2);
    float* slots    = (float*)alloc((size_t)Bb * NS * Dd * 4);
    _Float16* qh    = (_Float16*)alloc((size_t)Bb * NS * Dd * 2);
    float* rawp     = (float*)alloc((size_t)CHUNKS * Bb * NS * Dd * 4);  // 8 MB
    float* sumsp    = (float*)alloc((size_t)CHUNKS * Bb * NS * 4);
    float* ubuf     = (float*)alloc((size_t)Bb * NS * Dd * 4);
    float* gi       = (float*)alloc((size_t)Bb * NS * 1536 * 4);
    float* gh       = (float*)alloc((size_t)Bb * NS * 1536 * 4);
    _Float16* A2    = (_Float16*)alloc((size_t)512 * 1024 * 2);
    _Float16* P1    = (_Float16*)alloc((size_t)256 * 1024 * 2);
    _Float16* P2    = (_Float16*)alloc((size_t)256 * 2048 * 2);
    _Float16* P3    = (_Float16*)alloc((size_t)256 * 2048 * 2);
    _Float16* P4    = (_Float16*)alloc((size_t)256 * 1024 * 2);

    // ---- prep ----
    megapack_kernel<<<16896, 256, 0, stream>>>(
        k_w, v_w, w_ih, w_hh, mlp1_w, mlp2_w, mlp3_w, mlp4_w,
        Bkv, Bih, Bhh, Bm1, Bm2, Bm3, Bm4);
    pack_ln_single_kernel<<<MR / 4, 256, 0, stream>>>(inputs, ln_in_g, ln_in_b, Apack);
    slots_init_kernel<<<64, 256, 0, stream>>>(noise, mu, lsig, slots, A2, ln_s_g, ln_s_b, qh);

    kv_hgemm256_kernel<<<1024, 512, 0, stream>>>(Apack, Bkv, k_b, v_b, khalf, vT);

    for (int it = 0; it < ITERS; ++it) {
        attn_kernel<<<dim3(CHUNKS, Bb), 256, 0, stream>>>(qh, khalf, vT, rawp, sumsp);
        finalize_kernel<<<512, 256, 0, stream>>>(rawp, sumsp, ubuf, out0, A2);
        gru_gemm_kernel<<<dim3(24, 8), 256, 0, stream>>>(A2, Bih, Bhh, b_ih, b_hh, gi, gh);
        gru_elem_kernel<<<64, 256, 0, stream>>>(gi, gh, ubuf, slots, A2,
                                                ln_s_g, ln_s_b, qh,
                                                ln_p_g, ln_p_b, P1, it == ITERS - 1 ? 1 : 0);
    }

    // ---- output MLP ----
    hgemm64_kernel<1, 1><<<dim3(16, 4), 256, 0, stream>>>(P1, Bm1, mlp1_b, nullptr, P2, 1024, 1024, 1024);
    hgemm64_kernel<1, 1><<<dim3(16, 4), 256, 0, stream>>>(P2, Bm2, mlp2_b, nullptr, P3, 2048, 1024, 1024);
    hgemm64_kernel<1, 1><<<dim3(8, 4), 256, 0, stream>>>(P3, Bm3, mlp3_b, nullptr, P4, 2048, 512, 512);
    hgemm64_kernel<0, 0><<<dim3(4, 4), 256, 0, stream>>>(P4, Bm4, mlp4_b, out1, nullptr, 1024, 256, 256);
}

// Round 5
// 594.364 us; speedup vs baseline: 1.1555x; 1.1555x over previous
//
#include <hip/hip_runtime.h>
#include <math.h>

#define Bb 32
#define Nn 2048
#define Dd 512
#define NS 8
#define ITERS 3
#define EPSf 1e-8f
#define SCALEf 0.04419417382415922f   // 512^-0.5
#define LN_EPSf 1e-5f

#define QHS 520    // qh LDS row stride (halves)
#define PTS 136    // pT LDS row stride (halves)
#define CHUNKS 16  // attention token chunks (128 tokens each)

typedef _Float16 half8 __attribute__((ext_vector_type(8)));
typedef float f32x4 __attribute__((ext_vector_type(4)));

__device__ __forceinline__ float waveReduceSum(float v) {
    #pragma unroll
    for (int m = 32; m >= 1; m >>= 1) v += __shfl_xor(v, m);
    return v;
}

__device__ __forceinline__ float gelu_exact(float x) {
    return 0.5f * x * (1.0f + erff(x * 0.7071067811865476f));
}

__device__ __forceinline__ void async_copy16(const _Float16* g, _Float16* l) {
    __builtin_amdgcn_global_load_lds(
        (const __attribute__((address_space(1))) unsigned int*)g,
        (__attribute__((address_space(3))) unsigned int*)l, 16, 0, 0);
}

// ================= pack kernels =================
__global__ __launch_bounds__(256) void megapack_kernel(
    const float* __restrict__ k_w, const float* __restrict__ v_w,
    const float* __restrict__ w_ih, const float* __restrict__ w_hh,
    const float* __restrict__ m1, const float* __restrict__ m2,
    const float* __restrict__ m3, const float* __restrict__ m4,
    _Float16* __restrict__ Bkv, _Float16* __restrict__ Bih, _Float16* __restrict__ Bhh,
    _Float16* __restrict__ Bm1, _Float16* __restrict__ Bm2,
    _Float16* __restrict__ Bm3, _Float16* __restrict__ Bm4) {
    int bid = blockIdx.x, tid = threadIdx.x;
    const float* src; _Float16* dst; int kbits, base;
    if (bid < 2048) {   // kv plain copy
        int i = bid * 256 + tid;
        Bkv[i] = (_Float16)(i < 262144 ? k_w[i] : v_w[i - 262144]);
        return;
    }
    else if (bid < 5120)  { src = w_ih; dst = Bih; kbits = 9;  base = 2048; }
    else if (bid < 8192)  { src = w_hh; dst = Bhh; kbits = 9;  base = 5120; }
    else if (bid < 10240) { src = m1;   dst = Bm1; kbits = 9;  base = 8192; }
    else if (bid < 14336) { src = m2;   dst = Bm2; kbits = 10; base = 10240; }
    else if (bid < 16384) { src = m3;   dst = Bm3; kbits = 10; base = 14336; }
    else                  { src = m4;   dst = Bm4; kbits = 9;  base = 16384; }
    int e = (bid - base) * 256 + tid;
    int K = 1 << kbits;
    int row = e >> kbits, k = e & (K - 1);
    _Float16 h = (_Float16)src[e];
    _Float16* d = dst + ((size_t)row << (kbits + 1));
    d[k] = h;
    d[K + k] = h;
}

// LN(inputs) -> Apack fp16 [65536][512]
__global__ __launch_bounds__(256) void pack_ln_single_kernel(
    const float* __restrict__ x, const float* __restrict__ g, const float* __restrict__ b,
    _Float16* __restrict__ Ap) {
    int wid = blockIdx.x * 4 + (threadIdx.x >> 6);
    int lane = threadIdx.x & 63;
    const float4* row4 = (const float4*)(x + (size_t)wid * Dd);
    float4 va = row4[lane * 2], vb = row4[lane * 2 + 1];
    float v[8] = {va.x, va.y, va.z, va.w, vb.x, vb.y, vb.z, vb.w};
    float s = 0.f, sq = 0.f;
    #pragma unroll
    for (int t = 0; t < 8; ++t) { s += v[t]; sq += v[t] * v[t]; }
    s = waveReduceSum(s);
    sq = waveReduceSum(sq);
    float m = s * (1.0f / Dd);
    float var = sq * (1.0f / Dd) - m * m;
    float rs = rsqrtf(var + LN_EPSf);
    const float4* g4 = (const float4*)g;
    const float4* b4 = (const float4*)b;
    float4 ga = g4[lane * 2], gb = g4[lane * 2 + 1];
    float4 ba = b4[lane * 2], bb = b4[lane * 2 + 1];
    float gg[8] = {ga.x, ga.y, ga.z, ga.w, gb.x, gb.y, gb.z, gb.w};
    float bbv[8] = {ba.x, ba.y, ba.z, ba.w, bb.x, bb.y, bb.z, bb.w};
    half8 o;
    #pragma unroll
    for (int t = 0; t < 8; ++t) o[t] = (_Float16)((v[t] - m) * rs * gg[t] + bbv[t]);
    *(half8*)(Ap + (size_t)wid * Dd + lane * 8) = o;
}

// slots init, wave-per-row: slots fp32, A2 slot-rows (hi|lo), qh = LN(slots)*scale fp16
__global__ __launch_bounds__(256) void slots_init_kernel(
    const float* __restrict__ noise, const float* __restrict__ mu,
    const float* __restrict__ ls, float* __restrict__ slots, _Float16* __restrict__ A2,
    const float* __restrict__ lns_g, const float* __restrict__ lns_b,
    _Float16* __restrict__ qh) {
    int row = blockIdx.x * 4 + (threadIdx.x >> 6);
    int lane = threadIdx.x & 63;
    float val[8];
    float s = 0.f, sq = 0.f;
    #pragma unroll
    for (int t = 0; t < 8; ++t) {
        int d = t * 64 + lane;
        float v = mu[d] + expf(ls[d]) * noise[(size_t)row * 512 + d];
        val[t] = v;
        s += v; sq += v * v;
        slots[(size_t)row * 512 + d] = v;
        _Float16 hi = (_Float16)v;
        A2[(size_t)(256 + row) * 1024 + d] = hi;
        A2[(size_t)(256 + row) * 1024 + 512 + d] = (_Float16)(v - (float)hi);
    }
    s = waveReduceSum(s);
    sq = waveReduceSum(sq);
    float m = s * (1.0f / Dd);
    float var = sq * (1.0f / Dd) - m * m;
    float rs = rsqrtf(var + LN_EPSf);
    #pragma unroll
    for (int t = 0; t < 8; ++t) {
        int d = t * 64 + lane;
        qh[(size_t)row * 512 + d] = (_Float16)(((val[t] - m) * rs * lns_g[d] + lns_b[d]) * SCALEf);
    }
}

// ================= kv projection: 256x256 tile, 2-phase counted-vmcnt pipeline =================
// (verified R3 config: 102 us, absmax 2.44e-4; R4's deeper frag pipeline spilled to scratch)
// M=65536, N=1024, K=512. BK=64, 8 K-tiles. 8 waves (2m x 4n), per-wave 128x64 out.
// Phase split by M-half: p0 = acc rows 0-3 (32 MFMA), p1 = rows 4-7 (32 MFMA).
// B fragments read ONCE per K-tile in p0, held in regs through p1.
// Waits: end-p0 vmcnt(6), end-p1 vmcnt(4). Never vmcnt(0) in the main loop.

__global__ __launch_bounds__(512, 2) void kv_hgemm256_kernel(
    const _Float16* __restrict__ Apack, const _Float16* __restrict__ Bkv,
    const float* __restrict__ k_b, const float* __restrict__ v_b,
    _Float16* __restrict__ khalf, _Float16* __restrict__ vT) {
    __shared__ _Float16 lds[4][16384];   // [parity*2 + (0=A,1=B)][256 rows x 64 halves]
    const int f = blockIdx.x;
    const int swz = ((f & 7) << 7) + (f >> 3);     // 1024 % 8 == 0: bijective XCD swizzle
    const int m0 = (swz >> 2) << 8;
    const int n0 = (swz & 3) << 8;
    const int tid = threadIdx.x;
    const int lane = tid & 63;
    const int wid = tid >> 6;
    const int lr = lane & 15, quad = lane >> 4;
    const int wm = wid >> 2, wn = wid & 3;
    const int grow = tid >> 3;                                  // 0..63
    const int sslot = ((tid & 7) ^ (grow & 7)) << 3;            // halves
    const int lwave = wid << 9;                                 // wid*512 halves = 1 KB

    f32x4 acc[8][4];
    #pragma unroll
    for (int i = 0; i < 8; ++i)
        #pragma unroll
        for (int j = 0; j < 4; ++j) acc[i][j] = (f32x4){0.f, 0.f, 0.f, 0.f};

    auto stageA = [&](int ktile, int par, int g) {
        const _Float16* src = Apack + (size_t)(m0 + (g << 6) + grow) * 512 +
                              ((ktile & 7) << 6) + sslot;
        async_copy16(src, &lds[par * 2][(g << 12) + lwave]);
    };
    auto stageB = [&](int ktile, int par, int g) {
        const _Float16* src = Bkv + (size_t)(n0 + (g << 6) + grow) * 512 +
                              ((ktile & 7) << 6) + sslot;
        async_copy16(src, &lds[par * 2 + 1][(g << 12) + lwave]);
    };

    // prologue: match steady-state FIFO [.., A1,A3(t), A0,A2(t+1)]
    stageA(0, 0, 0); stageA(0, 0, 2);
    stageB(0, 0, 0); stageB(0, 0, 1); stageB(0, 0, 2); stageB(0, 0, 3);
    stageA(0, 0, 1); stageA(0, 0, 3);
    stageA(1, 1, 0); stageA(1, 1, 2);
    asm volatile("s_waitcnt vmcnt(4)" ::: "memory");
    __builtin_amdgcn_s_barrier();

    #pragma unroll 2
    for (int t = 0; t < 8; ++t) {
        const int cur = t & 1, nxt = cur ^ 1;
        const _Float16* Alds = &lds[cur * 2][0];
        const _Float16* Blds = &lds[cur * 2 + 1][0];
        half8 bf[4][2];
        // ---------- p0: C rows 0-3 (m-half 0), read B once ----------
        {
            half8 af[4][2];
            #pragma unroll
            for (int mt = 0; mt < 4; ++mt)
                #pragma unroll
                for (int kk = 0; kk < 2; ++kk) {
                    int R = wm * 128 + mt * 16 + lr;
                    af[mt][kk] = *(const half8*)(Alds + R * 64 +
                                 ((((kk << 2) | quad) ^ (lr & 7)) << 3));
                }
            #pragma unroll
            for (int nt = 0; nt < 4; ++nt)
                #pragma unroll
                for (int kk = 0; kk < 2; ++kk) {
                    int R = wn * 64 + nt * 16 + lr;
                    bf[nt][kk] = *(const half8*)(Blds + R * 64 +
                                 ((((kk << 2) | quad) ^ (lr & 7)) << 3));
                }
            stageB(t + 1, nxt, 0); stageB(t + 1, nxt, 1);
            stageB(t + 1, nxt, 2); stageB(t + 1, nxt, 3);
            __builtin_amdgcn_s_barrier();
            asm volatile("s_waitcnt lgkmcnt(0)" ::: "memory");
            __builtin_amdgcn_sched_barrier(0);
            __builtin_amdgcn_s_setprio(1);
            #pragma unroll
            for (int mt = 0; mt < 4; ++mt)
                #pragma unroll
                for (int nt = 0; nt < 4; ++nt)
                    #pragma unroll
                    for (int kk = 0; kk < 2; ++kk)
                        acc[mt][nt] = __builtin_amdgcn_mfma_f32_16x16x32_f16(
                            af[mt][kk], bf[nt][kk], acc[mt][nt], 0, 0, 0);
            __builtin_amdgcn_s_setprio(0);
            asm volatile("s_waitcnt vmcnt(6)" ::: "memory");
            __builtin_amdgcn_s_barrier();
        }
        // ---------- p1: C rows 4-7 (m-half 1), reuse bf ----------
        {
            half8 af[4][2];
            #pragma unroll
            for (int mt = 0; mt < 4; ++mt)
                #pragma unroll
                for (int kk = 0; kk < 2; ++kk) {
                    int R = wm * 128 + 64 + mt * 16 + lr;
                    af[mt][kk] = *(const half8*)(Alds + R * 64 +
                                 ((((kk << 2) | quad) ^ (lr & 7)) << 3));
                }
            stageA(t + 1, nxt, 1); stageA(t + 1, nxt, 3);
            stageA(t + 2, cur, 0); stageA(t + 2, cur, 2);
            __builtin_amdgcn_s_barrier();
            asm volatile("s_waitcnt lgkmcnt(0)" ::: "memory");
            __builtin_amdgcn_sched_barrier(0);
            __builtin_amdgcn_s_setprio(1);
            #pragma unroll
            for (int mt = 0; mt < 4; ++mt)
                #pragma unroll
                for (int nt = 0; nt < 4; ++nt)
                    #pragma unroll
                    for (int kk = 0; kk < 2; ++kk)
                        acc[4 + mt][nt] = __builtin_amdgcn_mfma_f32_16x16x32_f16(
                            af[mt][kk], bf[nt][kk], acc[4 + mt][nt], 0, 0, 0);
            __builtin_amdgcn_s_setprio(0);
            asm volatile("s_waitcnt vmcnt(4)" ::: "memory");
            __builtin_amdgcn_s_barrier();
        }
    }

    // drain tail DMA (wrapped garbage stages still in flight) before reusing LDS
    asm volatile("s_waitcnt vmcnt(0)" ::: "memory");
    __builtin_amdgcn_s_barrier();

    // ---- epilogue: stage C through LDS (XOR-swizzled), coalesced half8 stores ----
    _Float16* Cs = &lds[0][0];
    const bool isK = (n0 < 512);
    #pragma unroll
    for (int mt = 0; mt < 8; ++mt)
        #pragma unroll
        for (int nt = 0; nt < 4; ++nt) {
            int n = wn * 64 + nt * 16 + lr;
            float bv = isK ? k_b[n0 + n] : v_b[n0 - 512 + n];
            #pragma unroll
            for (int r = 0; r < 4; ++r) {
                int m = wm * 128 + mt * 16 + quad * 4 + r;
                float val = acc[mt][nt][r] + bv;
                int row = isK ? m : n;     // K: [token][feat]; V: [feat][token]
                int col = isK ? n : m;
                int byt = (row << 9) + ((col << 1) ^ ((row & 7) << 4));
                *(_Float16*)((char*)Cs + byt) = (_Float16)val;
            }
        }
    asm volatile("s_waitcnt lgkmcnt(0)" ::: "memory");
    __builtin_amdgcn_s_barrier();

    const int rr = (wid << 1) + (lane >> 5);   // 0..15 (2 rows per wave per pass)
    const int sl = lane & 31;                  // 16B slot within 512B row
    if (isK) {
        _Float16* dst0 = khalf + (size_t)m0 * 512 + n0;
        #pragma unroll
        for (int p = 0; p < 16; ++p) {
            int row = p * 16 + rr;
            int byt = (row << 9) + (((sl ^ (row & 7)) & 31) << 4);
            *(half8*)(dst0 + (size_t)row * 512 + sl * 8) = *(const half8*)((char*)Cs + byt);
        }
    } else {
        int b = m0 >> 11, j0 = m0 & 2047, d0 = n0 - 512;
        _Float16* dst0 = vT + ((size_t)b * 512 + d0) * 2048 + j0;
        #pragma unroll
        for (int p = 0; p < 16; ++p) {
            int row = p * 16 + rr;
            int byt = (row << 9) + (((sl ^ (row & 7)) & 31) << 4);
            *(half8*)(dst0 + (size_t)row * 2048 + sl * 8) = *(const half8*)((char*)Cs + byt);
        }
    }
}

// ================= fused attention iteration: 512 thr / 8 waves (latency fix) =================
// Wave w handles 16 tokens (QK) and a 64-wide d-slice (PV). 2 blocks/CU -> 16 waves/CU,
// 2x outstanding global loads vs the 4-wave version (attn is HBM-latency-bound: 128 MB/launch).
__global__ __launch_bounds__(512) void attn_kernel(
    const _Float16* __restrict__ qh_g,
    const _Float16* __restrict__ khalf, const _Float16* __restrict__ vT,
    float* __restrict__ rawp, float* __restrict__ sumsp) {
    const int b = blockIdx.y, chunk = blockIdx.x;
    __shared__ _Float16 qh[16 * QHS];
    __shared__ _Float16 pT[16 * PTS];
    __shared__ float sums_lds[128];
    const int tid = threadIdx.x, w = tid >> 6, lane = tid & 63;
    const int lr = lane & 15, quad = lane >> 4;

    // copy qh rows 0..7 (8 KB) from global; zero rows 8..15 (one half8 each, 512 thr)
    {
        int r = tid >> 6;               // 0..7
        int c = (tid & 63) * 8;         // 0..504
        *(half8*)(qh + r * QHS + c) = *(const half8*)(qh_g + ((size_t)b * NS + r) * 512 + c);
        half8 z = {};
        *(half8*)(qh + (8 + r) * QHS + c) = z;
    }
    __syncthreads();

    // QK: wave handles 16 tokens; A=k rows (m=token), B=qh (n=slot)
    const int j0 = chunk * 128 + w * 16;
    f32x4 dots = (f32x4){0.f, 0.f, 0.f, 0.f};
    #pragma unroll
    for (int ks = 0; ks < 16; ++ks) {
        half8 bq = *(const half8*)(qh + lr * QHS + ks * 32 + quad * 8);
        half8 ak = *(const half8*)(khalf + ((size_t)b * Nn + j0 + lr) * 512 + ks * 32 + quad * 8);
        dots = __builtin_amdgcn_mfma_f32_16x16x32_f16(ak, bq, dots, 0, 0, 0);
    }
    // softmax over slots (slot = lr, reduce over lr low 3 bits; token = quad*4+r)
    float ssum = 0.f;
    {
        f32x4 mx = dots;
        #pragma unroll
        for (int msk = 1; msk <= 4; msk <<= 1) {
            #pragma unroll
            for (int r = 0; r < 4; ++r) mx[r] = fmaxf(mx[r], __shfl_xor(mx[r], msk));
        }
        f32x4 p;
        #pragma unroll
        for (int r = 0; r < 4; ++r) p[r] = __expf(dots[r] - mx[r]);
        f32x4 sm = p;
        #pragma unroll
        for (int msk = 1; msk <= 4; msk <<= 1) {
            #pragma unroll
            for (int r = 0; r < 4; ++r) sm[r] += __shfl_xor(sm[r], msk);
        }
        #pragma unroll
        for (int r = 0; r < 4; ++r) {
            _Float16 ph = (_Float16)(p[r] / sm[r] + EPSf);
            pT[lr * PTS + w * 16 + quad * 4 + r] = ph;
            ssum += (float)ph;
        }
    }
    ssum += __shfl_xor(ssum, 16);
    ssum += __shfl_xor(ssum, 32);
    if (lane < 16) sums_lds[w * 16 + lane] = ssum;
    __syncthreads();

    // PV: A = P^T (m=slot, k=token), B = vT (n=d); wave covers d-range w*64
    f32x4 acc[4];
    #pragma unroll
    for (int nf = 0; nf < 4; ++nf) acc[nf] = (f32x4){0.f, 0.f, 0.f, 0.f};
    #pragma unroll
    for (int kc = 0; kc < 4; ++kc) {
        half8 ap = *(const half8*)(pT + lr * PTS + kc * 32 + quad * 8);
        #pragma unroll
        for (int nf = 0; nf < 4; ++nf) {
            int dcol = w * 64 + nf * 16 + lr;
            half8 bv = *(const half8*)(vT + ((size_t)b * 512 + dcol) * 2048 + chunk * 128 + kc * 32 + quad * 8);
            acc[nf] = __builtin_amdgcn_mfma_f32_16x16x32_f16(ap, bv, acc[nf], 0, 0, 0);
        }
    }
    if (quad < 2) {
        #pragma unroll
        for (int nf = 0; nf < 4; ++nf) {
            #pragma unroll
            for (int r = 0; r < 4; ++r) {
                int slot = quad * 4 + r;
                rawp[(((size_t)chunk * Bb + b) * NS + slot) * Dd + w * 64 + nf * 16 + lr] = acc[nf][r];
            }
        }
    }
    if (w == 0 && lane < NS) {
        float tot = 0.f;
        #pragma unroll
        for (int k = 0; k < 8; ++k) tot += sums_lds[k * 16 + lane];
        sumsp[((size_t)chunk * Bb + b) * NS + lane] = tot;
    }
}

// finalize: u = sum_c rawp / sum_c sumsp ; write ubuf, out0, and A2 u-rows (hi|lo)
__global__ __launch_bounds__(256) void finalize_kernel(
    const float* __restrict__ rawp, const float* __restrict__ sumsp,
    float* __restrict__ u, float* __restrict__ out0, _Float16* __restrict__ A2) {
    int idx = blockIdx.x * 256 + threadIdx.x;   // 131072
    int row = idx >> 9, k = idx & 511;
    float rs = 0.f, ss = 0.f;
    #pragma unroll
    for (int c = 0; c < CHUNKS; ++c) {
        rs += rawp[(size_t)c * 131072 + idx];
        ss += sumsp[c * 256 + row];
    }
    float val = rs / ss;
    u[idx] = val;
    out0[idx] = val;
    _Float16 hi = (_Float16)val;
    A2[(size_t)row * 1024 + k] = hi;
    A2[(size_t)row * 1024 + 512 + k] = (_Float16)(val - (float)hi);
}

// ================= 64-tile MFMA core (small gemms, LDS-staged — R3 best) =================
__device__ __forceinline__ void hgemm64_core(
    const _Float16* __restrict__ A, const _Float16* __restrict__ Bw,
    int K2, f32x4 acc[2][2], _Float16* As, _Float16* Bs) {
    const int tid = threadIdx.x;
    const int w = tid >> 6, lane = tid & 63;
    const int r8 = lane >> 3, seg = lane & 7;
    const int lr = lane & 15, quad = lane >> 4;
    const int wm = w >> 1, wn = w & 1;
    for (int k0 = 0; k0 < K2; k0 += 64) {
        __syncthreads();
        #pragma unroll
        for (int p = 0; p < 2; ++p) {
            int grp = p * 4 + w;
            int row = grp * 8 + r8;
            async_copy16(A + (size_t)row * K2 + k0 + seg * 8, As + grp * 512);
            async_copy16(Bw + (size_t)row * K2 + k0 + seg * 8, Bs + grp * 512);
        }
        __syncthreads();
        #pragma unroll
        for (int kk = 0; kk < 2; ++kk) {
            half8 a[2], b[2];
            #pragma unroll
            for (int t = 0; t < 2; ++t) {
                a[t] = *(const half8*)(As + (wm * 32 + t * 16 + lr) * 64 + kk * 32 + quad * 8);
                b[t] = *(const half8*)(Bs + (wn * 32 + t * 16 + lr) * 64 + kk * 32 + quad * 8);
            }
            #pragma unroll
            for (int mt = 0; mt < 2; ++mt)
                #pragma unroll
                for (int nt = 0; nt < 2; ++nt)
                    acc[mt][nt] = __builtin_amdgcn_mfma_f32_16x16x32_f16(
                        a[mt], b[nt], acc[mt][nt], 0, 0, 0);
        }
    }
}

// generic 64-tile gemm: C=act(A@Bw^T+bias); PACK -> write next-layer A (hi|lo, width Kp)
template <int ACT, int PACK>
__global__ __launch_bounds__(256) void hgemm64_kernel(
    const _Float16* __restrict__ A, const _Float16* __restrict__ Bw,
    const float* __restrict__ bias, float* __restrict__ C, _Float16* __restrict__ P,
    int K2, int N, int Kp) {
    __shared__ _Float16 As[4096], Bs[4096];
    const int m0 = blockIdx.y * 64, n0 = blockIdx.x * 64;
    f32x4 acc[2][2];
    #pragma unroll
    for (int i = 0; i < 2; ++i)
        #pragma unroll
        for (int j = 0; j < 2; ++j) acc[i][j] = (f32x4){0.f, 0.f, 0.f, 0.f};
    hgemm64_core(A + (size_t)m0 * K2, Bw + (size_t)n0 * K2, K2, acc, As, Bs);
    const int tid = threadIdx.x;
    const int w = tid >> 6, lane = tid & 63;
    const int lr = lane & 15, quad = lane >> 4;
    const int wm = w >> 1, wn = w & 1;
    #pragma unroll
    for (int mt = 0; mt < 2; ++mt)
        #pragma unroll
        for (int nt = 0; nt < 2; ++nt) {
            int n = n0 + wn * 32 + nt * 16 + lr;
            float bv = bias[n];
            #pragma unroll
            for (int r = 0; r < 4; ++r) {
                int m = m0 + wm * 32 + mt * 16 + quad * 4 + r;
                float val = acc[mt][nt][r] + bv;
                if (ACT) val = gelu_exact(val);
                if (PACK) {
                    _Float16 hi = (_Float16)val;
                    P[(size_t)m * 2 * Kp + n] = hi;
                    P[(size_t)m * 2 * Kp + Kp + n] = (_Float16)(val - (float)hi);
                } else {
                    C[(size_t)m * N + n] = val;
                }
            }
        }
}

// GRU gemms: by<4 -> gi = u@w_ih^T (A2 rows 0..255), else gh = slots@w_hh^T (rows 256..511)
__global__ __launch_bounds__(256) void gru_gemm_kernel(
    const _Float16* __restrict__ A2, const _Float16* __restrict__ Bih,
    const _Float16* __restrict__ Bhh, const float* __restrict__ b_ih,
    const float* __restrict__ b_hh, float* __restrict__ gi, float* __restrict__ gh) {
    __shared__ _Float16 As[4096], Bs[4096];
    const int by = blockIdx.y;
    const int n0 = blockIdx.x * 64;
    const _Float16* Ap; const _Float16* Bw; const float* bias; float* C;
    if (by < 4) { Ap = A2 + (size_t)by * 64 * 1024;        Bw = Bih; bias = b_ih; C = gi + (size_t)by * 64 * 1536; }
    else        { Ap = A2 + (size_t)(256 + (by - 4) * 64) * 1024; Bw = Bhh; bias = b_hh; C = gh + (size_t)(by - 4) * 64 * 1536; }
    f32x4 acc[2][2];
    #pragma unroll
    for (int i = 0; i < 2; ++i)
        #pragma unroll
        for (int j = 0; j < 2; ++j) acc[i][j] = (f32x4){0.f, 0.f, 0.f, 0.f};
    hgemm64_core(Ap, Bw + (size_t)n0 * 1024, 1024, acc, As, Bs);
    const int tid = threadIdx.x;
    const int w = tid >> 6, lane = tid & 63;
    const int lr = lane & 15, quad = lane >> 4;
    const int wm = w >> 1, wn = w & 1;
    #pragma unroll
    for (int mt = 0; mt < 2; ++mt)
        #pragma unroll
        for (int nt = 0; nt < 2; ++nt) {
            int n = n0 + wn * 32 + nt * 16 + lr;
            float bv = bias[n];
            #pragma unroll
            for (int r = 0; r < 4; ++r) {
                int m = wm * 32 + mt * 16 + quad * 4 + r;
                C[(size_t)m * 1536 + n] = acc[mt][nt][r] + bv;
            }
        }
}

// GRU elementwise, wave-per-row; slots + A2 slot-rows; qh for next iter, or P1 on last
__global__ __launch_bounds__(256) void gru_elem_kernel(
    const float* __restrict__ gi, const float* __restrict__ gh,
    const float* __restrict__ u, float* __restrict__ slots, _Float16* __restrict__ A2,
    const float* __restrict__ lns_g, const float* __restrict__ lns_b,
    _Float16* __restrict__ qh,
    const float* __restrict__ lnp_g, const float* __restrict__ lnp_b,
    _Float16* __restrict__ P1, int last) {
    int row = blockIdx.x * 4 + (threadIdx.x >> 6);
    int lane = threadIdx.x & 63;
    const float* gir = gi + (size_t)row * 1536;
    const float* ghr = gh + (size_t)row * 1536;
    float val[8];
    #pragma unroll
    for (int t = 0; t < 8; ++t) {
        int d = t * 64 + lane;
        float ir = gir[d], iz = gir[512 + d], in_ = gir[1024 + d];
        float hr = ghr[d], hz = ghr[512 + d], hn = ghr[1024 + d];
        float r = 1.0f / (1.0f + expf(-(ir + hr)));
        float z = 1.0f / (1.0f + expf(-(iz + hz)));
        float n = tanhf(in_ + r * hn);
        float h = slots[(size_t)row * 512 + d];
        float hnew = (1.0f - z) * n + z * h;
        float vv = u[(size_t)row * 512 + d] + hnew;
        val[t] = vv;
        slots[(size_t)row * 512 + d] = vv;
        _Float16 hi = (_Float16)vv;
        A2[(size_t)(256 + row) * 1024 + d] = hi;
        A2[(size_t)(256 + row) * 1024 + 512 + d] = (_Float16)(vv - (float)hi);
    }
    float s = 0.f, sq = 0.f;
    #pragma unroll
    for (int t = 0; t < 8; ++t) { s += val[t]; sq += val[t] * val[t]; }
    s = waveReduceSum(s);
    sq = waveReduceSum(sq);
    float m = s * (1.0f / Dd);
    float var = sq * (1.0f / Dd) - m * m;
    float rs = rsqrtf(var + LN_EPSf);
    if (!last) {
        #pragma unroll
        for (int t = 0; t < 8; ++t) {
            int d = t * 64 + lane;
            qh[(size_t)row * 512 + d] =
                (_Float16)(((val[t] - m) * rs * lns_g[d] + lns_b[d]) * SCALEf);
        }
    } else {
        #pragma unroll
        for (int t = 0; t < 8; ++t) {
            int d = t * 64 + lane;
            float a = (val[t] - m) * rs * lnp_g[d] + lnp_b[d];
            _Float16 hi = (_Float16)a;
            P1[(size_t)row * 1024 + d] = hi;
            P1[(size_t)row * 1024 + 512 + d] = (_Float16)(a - (float)hi);
        }
    }
}

// ================= launch =================
extern "C" void kernel_launch(void* const* d_in, const int* in_sizes, int n_in,
                              void* d_out, int out_size, void* d_ws, size_t ws_size,
                              hipStream_t stream) {
    const float* inputs   = (const float*)d_in[0];
    const float* noise    = (const float*)d_in[1];
    const float* mu       = (const float*)d_in[2];
    const float* lsig     = (const float*)d_in[3];
    const float* k_w      = (const float*)d_in[4];
    const float* k_b      = (const float*)d_in[5];
    const float* v_w      = (const float*)d_in[6];
    const float* v_b      = (const float*)d_in[7];
    const float* w_ih     = (const float*)d_in[8];
    const float* w_hh     = (const float*)d_in[9];
    const float* b_ih     = (const float*)d_in[10];
    const float* b_hh     = (const float*)d_in[11];
    const float* ln_in_g  = (const float*)d_in[12];
    const float* ln_in_b  = (const float*)d_in[13];
    const float* ln_s_g   = (const float*)d_in[14];
    const float* ln_s_b   = (const float*)d_in[15];
    const float* ln_p_g   = (const float*)d_in[16];
    const float* ln_p_b   = (const float*)d_in[17];
    const float* mlp1_w   = (const float*)d_in[18];
    const float* mlp1_b   = (const float*)d_in[19];
    const float* mlp2_w   = (const float*)d_in[20];
    const float* mlp2_b   = (const float*)d_in[21];
    const float* mlp3_w   = (const float*)d_in[22];
    const float* mlp3_b   = (const float*)d_in[23];
    const float* mlp4_w   = (const float*)d_in[24];
    const float* mlp4_b   = (const float*)d_in[25];
    float* out0 = (float*)d_out;                 // updates [32,8,512]
    float* out1 = (float*)d_out + Bb * NS * Dd;  // s [32,8,256]

    char* wp = (char*)d_ws;
    auto alloc = [&](size_t bytes) -> void* {
        void* p = (void*)wp;
        wp += (bytes + 255) & ~(size_t)255;
        return p;
    };
    const size_t MR = (size_t)Bb * Nn;  // 65536
    _Float16* Apack = (_Float16*)alloc(MR * 512 * 2);           // 67 MB
    _Float16* khalf = (_Float16*)alloc(MR * 512 * 2);           // 67 MB
    _Float16* vT    = (_Float16*)alloc((size_t)Bb * 512 * Nn * 2); // 67 MB
    _Float16* Bkv   = (_Float16*)alloc((size_t)1024 * 512 * 2);
    _Float16* Bih   = (_Float16*)alloc((size_t)1536 * 1024 * 2);
    _Float16* Bhh   = (_Float16*)alloc((size_t)1536 * 1024 * 2);
    _Float16* Bm1   = (_Float16*)alloc((size_t)1024 * 1024 * 2);
    _Float16* Bm2   = (_Float16*)alloc((size_t)1024 * 2048 * 2);
    _Float16* Bm3   = (_Float16*)alloc((size_t)512 * 2048 * 2);
    _Float16* Bm4   = (_Float16*)alloc((size_t)256 * 1024 * 2);
    float* slots    = (float*)alloc((size_t)Bb * NS * Dd * 4);
    _Float16* qh    = (_Float16*)alloc((size_t)Bb * NS * Dd * 2);
    float* rawp     = (float*)alloc((size_t)CHUNKS * Bb * NS * Dd * 4);  // 8 MB
    float* sumsp    = (float*)alloc((size_t)CHUNKS * Bb * NS * 4);
    float* ubuf     = (float*)alloc((size_t)Bb * NS * Dd * 4);
    float* gi       = (float*)alloc((size_t)Bb * NS * 1536 * 4);
    float* gh       = (float*)alloc((size_t)Bb * NS * 1536 * 4);
    _Float16* A2    = (_Float16*)alloc((size_t)512 * 1024 * 2);
    _Float16* P1    = (_Float16*)alloc((size_t)256 * 1024 * 2);
    _Float16* P2    = (_Float16*)alloc((size_t)256 * 2048 * 2);
    _Float16* P3    = (_Float16*)alloc((size_t)256 * 2048 * 2);
    _Float16* P4    = (_Float16*)alloc((size_t)256 * 1024 * 2);

    // ---- prep ----
    megapack_kernel<<<16896, 256, 0, stream>>>(
        k_w, v_w, w_ih, w_hh, mlp1_w, mlp2_w, mlp3_w, mlp4_w,
        Bkv, Bih, Bhh, Bm1, Bm2, Bm3, Bm4);
    pack_ln_single_kernel<<<MR / 4, 256, 0, stream>>>(inputs, ln_in_g, ln_in_b, Apack);
    slots_init_kernel<<<64, 256, 0, stream>>>(noise, mu, lsig, slots, A2, ln_s_g, ln_s_b, qh);

    kv_hgemm256_kernel<<<1024, 512, 0, stream>>>(Apack, Bkv, k_b, v_b, khalf, vT);

    for (int it = 0; it < ITERS; ++it) {
        attn_kernel<<<dim3(CHUNKS, Bb), 512, 0, stream>>>(qh, khalf, vT, rawp, sumsp);
        finalize_kernel<<<512, 256, 0, stream>>>(rawp, sumsp, ubuf, out0, A2);
        gru_gemm_kernel<<<dim3(24, 8), 256, 0, stream>>>(A2, Bih, Bhh, b_ih, b_hh, gi, gh);
        gru_elem_kernel<<<64, 256, 0, stream>>>(gi, gh, ubuf, slots, A2,
                                                ln_s_g, ln_s_b, qh,
                                                ln_p_g, ln_p_b, P1, it == ITERS - 1 ? 1 : 0);
    }

    // ---- output MLP ----
    hgemm64_kernel<1, 1><<<dim3(16, 4), 256, 0, stream>>>(P1, Bm1, mlp1_b, nullptr, P2, 1024, 1024, 1024);
    hgemm64_kernel<1, 1><<<dim3(16, 4), 256, 0, stream>>>(P2, Bm2, mlp2_b, nullptr, P3, 2048, 1024, 1024);
    hgemm64_kernel<1, 1><<<dim3(8, 4), 256, 0, stream>>>(P3, Bm3, mlp3_b, nullptr, P4, 2048, 512, 512);
    hgemm64_kernel<0, 0><<<dim3(4, 4), 256, 0, stream>>>(P4, Bm4, mlp4_b, out1, nullptr, 1024, 256, 256);
}

// Round 6
// 566.543 us; speedup vs baseline: 1.2123x; 1.0491x over previous
//
#include <hip/hip_runtime.h>
#include <math.h>

#define Bb 32
#define Nn 2048
#define Dd 512
#define NS 8
#define ITERS 3
#define EPSf 1e-8f
#define SCALEf 0.04419417382415922f   // 512^-0.5
#define LN_EPSf 1e-5f

#define CHUNKS 16  // attention token chunks (128 tokens each)
#define SUBT 32    // tokens per attn sub-tile

typedef _Float16 half8 __attribute__((ext_vector_type(8)));
typedef _Float16 half2v __attribute__((ext_vector_type(2)));
typedef float f32x4 __attribute__((ext_vector_type(4)));

__device__ __forceinline__ float waveReduceSum(float v) {
    #pragma unroll
    for (int m = 32; m >= 1; m >>= 1) v += __shfl_xor(v, m);
    return v;
}

__device__ __forceinline__ float gelu_exact(float x) {
    return 0.5f * x * (1.0f + erff(x * 0.7071067811865476f));
}

__device__ __forceinline__ void async_copy16(const _Float16* g, _Float16* l) {
    __builtin_amdgcn_global_load_lds(
        (const __attribute__((address_space(1))) unsigned int*)g,
        (__attribute__((address_space(3))) unsigned int*)l, 16, 0, 0);
}

// ================= pack kernels =================
// duplicate-K packs for hi|lo GEMMs: B rows stored [n][K | K] (value duplicated)
__global__ __launch_bounds__(256) void megapack_kernel(
    const float* __restrict__ w_ih, const float* __restrict__ w_hh,
    const float* __restrict__ m1, const float* __restrict__ m2,
    const float* __restrict__ m3, const float* __restrict__ m4,
    const float* __restrict__ v_w,
    _Float16* __restrict__ Bih, _Float16* __restrict__ Bhh,
    _Float16* __restrict__ Bm1, _Float16* __restrict__ Bm2,
    _Float16* __restrict__ Bm3, _Float16* __restrict__ Bm4,
    _Float16* __restrict__ Bvd) {
    int bid = blockIdx.x, tid = threadIdx.x;
    const float* src; _Float16* dst; int kbits, base;
    if      (bid < 3072)  { src = w_ih; dst = Bih; kbits = 9;  base = 0; }
    else if (bid < 6144)  { src = w_hh; dst = Bhh; kbits = 9;  base = 3072; }
    else if (bid < 8192)  { src = m1;   dst = Bm1; kbits = 9;  base = 6144; }
    else if (bid < 12288) { src = m2;   dst = Bm2; kbits = 10; base = 8192; }
    else if (bid < 14336) { src = m3;   dst = Bm3; kbits = 10; base = 12288; }
    else if (bid < 14848) { src = m4;   dst = Bm4; kbits = 9;  base = 14336; }
    else                  { src = v_w;  dst = Bvd; kbits = 9;  base = 14848; }
    int e = (bid - base) * 256 + tid;
    int K = 1 << kbits;
    int row = e >> kbits, k = e & (K - 1);
    _Float16 h = (_Float16)src[e];
    _Float16* d = dst + ((size_t)row << (kbits + 1));
    d[k] = h;
    d[K + k] = h;
}

// k_w [f][d] f32 -> BkT [d][f] fp16 (LDS tile transpose)
__global__ __launch_bounds__(256) void kwt_kernel(
    const float* __restrict__ kw, _Float16* __restrict__ BkT) {
    __shared__ float t[64][65];
    const int bf = blockIdx.x * 64, bd = blockIdx.y * 64;
    const int tid = threadIdx.x;
    #pragma unroll
    for (int i = 0; i < 16; ++i) {
        int idx = i * 256 + tid;
        int r = idx >> 6, c = idx & 63;
        t[r][c] = kw[(size_t)(bf + r) * 512 + bd + c];
    }
    __syncthreads();
    #pragma unroll
    for (int i = 0; i < 16; ++i) {
        int idx = i * 256 + tid;
        int r = idx >> 6, c = idx & 63;
        BkT[(size_t)(bd + r) * 512 + bf + c] = (_Float16)t[c][r];
    }
}

// LN(inputs) -> Apack fp16 [65536][512]
__global__ __launch_bounds__(256) void pack_ln_single_kernel(
    const float* __restrict__ x, const float* __restrict__ g, const float* __restrict__ b,
    _Float16* __restrict__ Ap) {
    int wid = blockIdx.x * 4 + (threadIdx.x >> 6);
    int lane = threadIdx.x & 63;
    const float4* row4 = (const float4*)(x + (size_t)wid * Dd);
    float4 va = row4[lane * 2], vb = row4[lane * 2 + 1];
    float v[8] = {va.x, va.y, va.z, va.w, vb.x, vb.y, vb.z, vb.w};
    float s = 0.f, sq = 0.f;
    #pragma unroll
    for (int t = 0; t < 8; ++t) { s += v[t]; sq += v[t] * v[t]; }
    s = waveReduceSum(s);
    sq = waveReduceSum(sq);
    float m = s * (1.0f / Dd);
    float var = sq * (1.0f / Dd) - m * m;
    float rs = rsqrtf(var + LN_EPSf);
    const float4* g4 = (const float4*)g;
    const float4* b4 = (const float4*)b;
    float4 ga = g4[lane * 2], gb = g4[lane * 2 + 1];
    float4 ba = b4[lane * 2], bb = b4[lane * 2 + 1];
    float gg[8] = {ga.x, ga.y, ga.z, ga.w, gb.x, gb.y, gb.z, gb.w};
    float bbv[8] = {ba.x, ba.y, ba.z, ba.w, bb.x, bb.y, bb.z, bb.w};
    half8 o;
    #pragma unroll
    for (int t = 0; t < 8; ++t) o[t] = (_Float16)((v[t] - m) * rs * gg[t] + bbv[t]);
    *(half8*)(Ap + (size_t)wid * Dd + lane * 8) = o;
}

// slots init: slots fp32, A2 slot-rows (hi|lo), qh = LN(slots)*scale fp16, cvec = qh . k_b
__global__ __launch_bounds__(256) void slots_init_kernel(
    const float* __restrict__ noise, const float* __restrict__ mu,
    const float* __restrict__ ls, float* __restrict__ slots, _Float16* __restrict__ A2,
    const float* __restrict__ lns_g, const float* __restrict__ lns_b,
    _Float16* __restrict__ qh, const float* __restrict__ k_b, float* __restrict__ cvec) {
    int row = blockIdx.x * 4 + (threadIdx.x >> 6);
    int lane = threadIdx.x & 63;
    float val[8];
    float s = 0.f, sq = 0.f;
    #pragma unroll
    for (int t = 0; t < 8; ++t) {
        int d = t * 64 + lane;
        float v = mu[d] + expf(ls[d]) * noise[(size_t)row * 512 + d];
        val[t] = v;
        s += v; sq += v * v;
        slots[(size_t)row * 512 + d] = v;
        _Float16 hi = (_Float16)v;
        A2[(size_t)(256 + row) * 1024 + d] = hi;
        A2[(size_t)(256 + row) * 1024 + 512 + d] = (_Float16)(v - (float)hi);
    }
    s = waveReduceSum(s);
    sq = waveReduceSum(sq);
    float m = s * (1.0f / Dd);
    float var = sq * (1.0f / Dd) - m * m;
    float rs = rsqrtf(var + LN_EPSf);
    float c = 0.f;
    #pragma unroll
    for (int t = 0; t < 8; ++t) {
        int d = t * 64 + lane;
        float qv = ((val[t] - m) * rs * lns_g[d] + lns_b[d]) * SCALEf;
        qh[(size_t)row * 512 + d] = (_Float16)qv;
        c += qv * k_b[d];
    }
    c = waveReduceSum(c);
    if (lane == 0) cvec[row] = c;
}

// ================= fused attention: single-X-read formulation =================
// dots[token, slot] = X . qk^T (hi|lo) + c_slot ; softmax over slots; renorm deferred.
// W[slot, d] += attn * X (VALU, f32 acc, fp16 attn). X streamed once: 64 MB/iter.
// Per block: batch b, 128-token chunk; 4 sub-tiles of 32 tokens, dbuf LDS (64 KB),
// counted vmcnt(8) staging, XOR slot swizzle (both sides). Waves: w&1 = m-tile,
// w>>1 = qk hi/lo half; lo-dots merged via LDS; PV by all 4 waves (128 d each).
__global__ __launch_bounds__(256) void attn_kernel(
    const _Float16* __restrict__ Apack, const _Float16* __restrict__ Qk,
    const float* __restrict__ cvec,
    float* __restrict__ rawp, float* __restrict__ sumsp) {
    const int b = blockIdx.y, chunk = blockIdx.x;
    __shared__ _Float16 Xs[2][SUBT * 512];   // 64 KB
    __shared__ _Float16 aTh[SUBT][8];        // attn fp16 [token][slot]
    __shared__ float dlo[SUBT][8];           // lo-half dots
    __shared__ float sred[2][8];
    const int tid = threadIdx.x, w = tid >> 6, lane = tid & 63;
    const int lr = lane & 15, quad = lane >> 4;
    const int mt = w & 1, hl = w >> 1;
    const size_t tokbase = (size_t)b * Nn + chunk * 128;

    const float cv = cvec[b * 8 + (lr & 7)];
    const _Float16* qkrow = Qk + ((size_t)(b * 8 + (lr & 7)) << 10) + hl * 512;

    float2 w8[8];
    #pragma unroll
    for (int s = 0; s < 8; ++s) w8[s] = (float2){0.f, 0.f};
    float ssum_part = 0.f;
    const int d0 = w * 128 + lane * 2;
    const int pvslot = d0 >> 3, pvsub = d0 & 7;

    auto STAGE = [&](int st, int buf) {
        #pragma unroll
        for (int i = 0; i < 8; ++i) {
            int row = i * 4 + w;
            const _Float16* src = Apack + (tokbase + st * SUBT + row) * 512 +
                                  ((lane ^ (row & 7)) << 3);
            async_copy16(src, &Xs[buf][row * 512]);
        }
    };

    STAGE(0, 0);
    for (int st = 0; st < 4; ++st) {
        const int cur = st & 1;
        STAGE(st < 3 ? st + 1 : 3, cur ^ 1);
        asm volatile("s_waitcnt vmcnt(8)" ::: "memory");
        __syncthreads();
        const _Float16* Xc = &Xs[cur][0];
        // ---- QK: wave computes its m-tile x its qk-half ----
        f32x4 dots = (f32x4){0.f, 0.f, 0.f, 0.f};
        const int rr = mt * 16 + lr;
        #pragma unroll
        for (int ks = 0; ks < 16; ++ks) {
            half8 ax = *(const half8*)(Xc + rr * 512 +
                       ((((ks << 2) | quad) ^ (rr & 7)) << 3));
            half8 bq = *(const half8*)(qkrow + ks * 32 + quad * 8);
            dots = __builtin_amdgcn_mfma_f32_16x16x32_f16(ax, bq, dots, 0, 0, 0);
        }
        if (hl == 1 && lr < 8) {
            #pragma unroll
            for (int r = 0; r < 4; ++r) dlo[mt * 16 + quad * 4 + r][lr] = dots[r];
        }
        __syncthreads();
        if (hl == 0) {
            f32x4 d;
            #pragma unroll
            for (int r = 0; r < 4; ++r)
                d[r] = dots[r] + dlo[mt * 16 + quad * 4 + r][lr & 7] + cv;
            f32x4 mx = d;
            #pragma unroll
            for (int msk = 1; msk <= 4; msk <<= 1) {
                #pragma unroll
                for (int r = 0; r < 4; ++r) mx[r] = fmaxf(mx[r], __shfl_xor(mx[r], msk));
            }
            f32x4 p;
            #pragma unroll
            for (int r = 0; r < 4; ++r) p[r] = __expf(d[r] - mx[r]);
            f32x4 sm = p;
            #pragma unroll
            for (int msk = 1; msk <= 4; msk <<= 1) {
                #pragma unroll
                for (int r = 0; r < 4; ++r) sm[r] += __shfl_xor(sm[r], msk);
            }
            #pragma unroll
            for (int r = 0; r < 4; ++r) {
                _Float16 ph = (_Float16)(p[r] / sm[r] + EPSf);
                if (lr < 8) aTh[mt * 16 + quad * 4 + r][lr] = ph;
                ssum_part += (float)ph;
            }
        }
        __syncthreads();
        // ---- PV (all waves): W[slot][d-pair] += a * x, f32 acc ----
        #pragma unroll 4
        for (int t = 0; t < SUBT; ++t) {
            half8 aa = *(const half8*)&aTh[t][0];
            half2v xv = *(const half2v*)(Xc + t * 512 +
                        ((pvslot ^ (t & 7)) << 3) + pvsub);
            float x0 = (float)xv[0], x1 = (float)xv[1];
            #pragma unroll
            for (int s = 0; s < 8; ++s) {
                float av = (float)aa[s];
                w8[s].x += av * x0;
                w8[s].y += av * x1;
            }
        }
        __syncthreads();
    }
    asm volatile("s_waitcnt vmcnt(0)" ::: "memory");

    float* rp = rawp + ((size_t)chunk * Bb + b) * NS * Dd + d0;
    #pragma unroll
    for (int s = 0; s < 8; ++s) *(float2*)(rp + s * Dd) = w8[s];

    ssum_part += __shfl_xor(ssum_part, 16);
    ssum_part += __shfl_xor(ssum_part, 32);
    if (hl == 0 && lane < 8) sred[w][lane] = ssum_part;
    __syncthreads();
    if (tid < 8) sumsp[((size_t)chunk * Bb + b) * NS + tid] = sred[0][tid] + sred[1][tid];
}

// finalize: W = sum_c rawp / sum_c sumsp -> Whl hi|lo fp16 [256][1024]
__global__ __launch_bounds__(256) void finalize_kernel(
    const float* __restrict__ rawp, const float* __restrict__ sumsp,
    _Float16* __restrict__ Whl) {
    int idx = blockIdx.x * 256 + threadIdx.x;   // 131072
    int row = idx >> 9, d = idx & 511;
    float rs = 0.f, ss = 0.f;
    #pragma unroll
    for (int c = 0; c < CHUNKS; ++c) {
        rs += rawp[(size_t)c * 131072 + idx];
        ss += sumsp[c * 256 + row];
    }
    float val = rs / ss;
    _Float16 hi = (_Float16)val;
    Whl[(size_t)row * 1024 + d] = hi;
    Whl[(size_t)row * 1024 + 512 + d] = (_Float16)(val - (float)hi);
}

// ================= 64-tile MFMA core (small gemms, LDS-staged) =================
__device__ __forceinline__ void hgemm64_core(
    const _Float16* __restrict__ A, const _Float16* __restrict__ Bw,
    int K2, f32x4 acc[2][2], _Float16* As, _Float16* Bs) {
    const int tid = threadIdx.x;
    const int w = tid >> 6, lane = tid & 63;
    const int r8 = lane >> 3, seg = lane & 7;
    const int lr = lane & 15, quad = lane >> 4;
    const int wm = w >> 1, wn = w & 1;
    for (int k0 = 0; k0 < K2; k0 += 64) {
        __syncthreads();
        #pragma unroll
        for (int p = 0; p < 2; ++p) {
            int grp = p * 4 + w;
            int row = grp * 8 + r8;
            async_copy16(A + (size_t)row * K2 + k0 + seg * 8, As + grp * 512);
            async_copy16(Bw + (size_t)row * K2 + k0 + seg * 8, Bs + grp * 512);
        }
        __syncthreads();
        #pragma unroll
        for (int kk = 0; kk < 2; ++kk) {
            half8 a[2], b[2];
            #pragma unroll
            for (int t = 0; t < 2; ++t) {
                a[t] = *(const half8*)(As + (wm * 32 + t * 16 + lr) * 64 + kk * 32 + quad * 8);
                b[t] = *(const half8*)(Bs + (wn * 32 + t * 16 + lr) * 64 + kk * 32 + quad * 8);
            }
            #pragma unroll
            for (int mt = 0; mt < 2; ++mt)
                #pragma unroll
                for (int nt = 0; nt < 2; ++nt)
                    acc[mt][nt] = __builtin_amdgcn_mfma_f32_16x16x32_f16(
                        a[mt], b[nt], acc[mt][nt], 0, 0, 0);
        }
    }
}

// generic 64-tile gemm: C=act(A@Bw^T[+bias]); PACK -> write hi|lo A for next layer
template <int ACT, int PACK, int BIAS>
__global__ __launch_bounds__(256) void hgemm64_kernel(
    const _Float16* __restrict__ A, const _Float16* __restrict__ Bw,
    const float* __restrict__ bias, float* __restrict__ C, _Float16* __restrict__ P,
    int K2, int N, int Kp) {
    __shared__ _Float16 As[4096], Bs[4096];
    const int m0 = blockIdx.y * 64, n0 = blockIdx.x * 64;
    f32x4 acc[2][2];
    #pragma unroll
    for (int i = 0; i < 2; ++i)
        #pragma unroll
        for (int j = 0; j < 2; ++j) acc[i][j] = (f32x4){0.f, 0.f, 0.f, 0.f};
    hgemm64_core(A + (size_t)m0 * K2, Bw + (size_t)n0 * K2, K2, acc, As, Bs);
    const int tid = threadIdx.x;
    const int w = tid >> 6, lane = tid & 63;
    const int lr = lane & 15, quad = lane >> 4;
    const int wm = w >> 1, wn = w & 1;
    #pragma unroll
    for (int mt = 0; mt < 2; ++mt)
        #pragma unroll
        for (int nt = 0; nt < 2; ++nt) {
            int n = n0 + wn * 32 + nt * 16 + lr;
            float bv = BIAS ? bias[n] : 0.f;
            #pragma unroll
            for (int r = 0; r < 4; ++r) {
                int m = m0 + wm * 32 + mt * 16 + quad * 4 + r;
                float val = acc[mt][nt][r] + bv;
                if (ACT) val = gelu_exact(val);
                if (PACK) {
                    _Float16 hi = (_Float16)val;
                    P[(size_t)m * 2 * Kp + n] = hi;
                    P[(size_t)m * 2 * Kp + Kp + n] = (_Float16)(val - (float)hi);
                } else {
                    C[(size_t)m * N + n] = val;
                }
            }
        }
}

// u-gemm: u = Whl @ v_w^T + v_b ; writes ubuf, out0, A2 u-rows (hi|lo)
__global__ __launch_bounds__(256) void ugemm_kernel(
    const _Float16* __restrict__ Whl, const _Float16* __restrict__ Bvd,
    const float* __restrict__ v_b, float* __restrict__ u, float* __restrict__ out0,
    _Float16* __restrict__ A2) {
    __shared__ _Float16 As[4096], Bs[4096];
    const int m0 = blockIdx.y * 64, n0 = blockIdx.x * 64;
    f32x4 acc[2][2];
    #pragma unroll
    for (int i = 0; i < 2; ++i)
        #pragma unroll
        for (int j = 0; j < 2; ++j) acc[i][j] = (f32x4){0.f, 0.f, 0.f, 0.f};
    hgemm64_core(Whl + (size_t)m0 * 1024, Bvd + (size_t)n0 * 1024, 1024, acc, As, Bs);
    const int tid = threadIdx.x;
    const int w = tid >> 6, lane = tid & 63;
    const int lr = lane & 15, quad = lane >> 4;
    const int wm = w >> 1, wn = w & 1;
    #pragma unroll
    for (int mt = 0; mt < 2; ++mt)
        #pragma unroll
        for (int nt = 0; nt < 2; ++nt) {
            int n = n0 + wn * 32 + nt * 16 + lr;
            float bv = v_b[n];
            #pragma unroll
            for (int r = 0; r < 4; ++r) {
                int m = m0 + wm * 32 + mt * 16 + quad * 4 + r;
                float val = acc[mt][nt][r] + bv;
                u[(size_t)m * 512 + n] = val;
                out0[(size_t)m * 512 + n] = val;
                _Float16 hi = (_Float16)val;
                A2[(size_t)m * 1024 + n] = hi;
                A2[(size_t)m * 1024 + 512 + n] = (_Float16)(val - (float)hi);
            }
        }
}

// GRU gemms: by<4 -> gi = u@w_ih^T (A2 rows 0..255), else gh = slots@w_hh^T (rows 256..511)
__global__ __launch_bounds__(256) void gru_gemm_kernel(
    const _Float16* __restrict__ A2, const _Float16* __restrict__ Bih,
    const _Float16* __restrict__ Bhh, const float* __restrict__ b_ih,
    const float* __restrict__ b_hh, float* __restrict__ gi, float* __restrict__ gh) {
    __shared__ _Float16 As[4096], Bs[4096];
    const int by = blockIdx.y;
    const int n0 = blockIdx.x * 64;
    const _Float16* Ap; const _Float16* Bw; const float* bias; float* C;
    if (by < 4) { Ap = A2 + (size_t)by * 64 * 1024;        Bw = Bih; bias = b_ih; C = gi + (size_t)by * 64 * 1536; }
    else        { Ap = A2 + (size_t)(256 + (by - 4) * 64) * 1024; Bw = Bhh; bias = b_hh; C = gh + (size_t)(by - 4) * 64 * 1536; }
    f32x4 acc[2][2];
    #pragma unroll
    for (int i = 0; i < 2; ++i)
        #pragma unroll
        for (int j = 0; j < 2; ++j) acc[i][j] = (f32x4){0.f, 0.f, 0.f, 0.f};
    hgemm64_core(Ap, Bw + (size_t)n0 * 1024, 1024, acc, As, Bs);
    const int tid = threadIdx.x;
    const int w = tid >> 6, lane = tid & 63;
    const int lr = lane & 15, quad = lane >> 4;
    const int wm = w >> 1, wn = w & 1;
    #pragma unroll
    for (int mt = 0; mt < 2; ++mt)
        #pragma unroll
        for (int nt = 0; nt < 2; ++nt) {
            int n = n0 + wn * 32 + nt * 16 + lr;
            float bv = bias[n];
            #pragma unroll
            for (int r = 0; r < 4; ++r) {
                int m = wm * 32 + mt * 16 + quad * 4 + r;
                C[(size_t)m * 1536 + n] = acc[mt][nt][r] + bv;
            }
        }
}

// GRU elementwise; slots + A2 slot-rows; qh+cvec for next iter, or P1 on last
__global__ __launch_bounds__(256) void gru_elem_kernel(
    const float* __restrict__ gi, const float* __restrict__ gh,
    const float* __restrict__ u, float* __restrict__ slots, _Float16* __restrict__ A2,
    const float* __restrict__ lns_g, const float* __restrict__ lns_b,
    _Float16* __restrict__ qh, const float* __restrict__ k_b, float* __restrict__ cvec,
    const float* __restrict__ lnp_g, const float* __restrict__ lnp_b,
    _Float16* __restrict__ P1, int last) {
    int row = blockIdx.x * 4 + (threadIdx.x >> 6);
    int lane = threadIdx.x & 63;
    const float* gir = gi + (size_t)row * 1536;
    const float* ghr = gh + (size_t)row * 1536;
    float val[8];
    #pragma unroll
    for (int t = 0; t < 8; ++t) {
        int d = t * 64 + lane;
        float ir = gir[d], iz = gir[512 + d], in_ = gir[1024 + d];
        float hr = ghr[d], hz = ghr[512 + d], hn = ghr[1024 + d];
        float r = 1.0f / (1.0f + expf(-(ir + hr)));
        float z = 1.0f / (1.0f + expf(-(iz + hz)));
        float n = tanhf(in_ + r * hn);
        float h = slots[(size_t)row * 512 + d];
        float hnew = (1.0f - z) * n + z * h;
        float vv = u[(size_t)row * 512 + d] + hnew;
        val[t] = vv;
        slots[(size_t)row * 512 + d] = vv;
        _Float16 hi = (_Float16)vv;
        A2[(size_t)(256 + row) * 1024 + d] = hi;
        A2[(size_t)(256 + row) * 1024 + 512 + d] = (_Float16)(vv - (float)hi);
    }
    float s = 0.f, sq = 0.f;
    #pragma unroll
    for (int t = 0; t < 8; ++t) { s += val[t]; sq += val[t] * val[t]; }
    s = waveReduceSum(s);
    sq = waveReduceSum(sq);
    float m = s * (1.0f / Dd);
    float var = sq * (1.0f / Dd) - m * m;
    float rs = rsqrtf(var + LN_EPSf);
    if (!last) {
        float c = 0.f;
        #pragma unroll
        for (int t = 0; t < 8; ++t) {
            int d = t * 64 + lane;
            float qv = ((val[t] - m) * rs * lns_g[d] + lns_b[d]) * SCALEf;
            qh[(size_t)row * 512 + d] = (_Float16)qv;
            c += qv * k_b[d];
        }
        c = waveReduceSum(c);
        if (lane == 0) cvec[row] = c;
    } else {
        #pragma unroll
        for (int t = 0; t < 8; ++t) {
            int d = t * 64 + lane;
            float a = (val[t] - m) * rs * lnp_g[d] + lnp_b[d];
            _Float16 hi = (_Float16)a;
            P1[(size_t)row * 1024 + d] = hi;
            P1[(size_t)row * 1024 + 512 + d] = (_Float16)(a - (float)hi);
        }
    }
}

// ================= launch =================
extern "C" void kernel_launch(void* const* d_in, const int* in_sizes, int n_in,
                              void* d_out, int out_size, void* d_ws, size_t ws_size,
                              hipStream_t stream) {
    const float* inputs   = (const float*)d_in[0];
    const float* noise    = (const float*)d_in[1];
    const float* mu       = (const float*)d_in[2];
    const float* lsig     = (const float*)d_in[3];
    const float* k_w      = (const float*)d_in[4];
    const float* k_b      = (const float*)d_in[5];
    const float* v_w      = (const float*)d_in[6];
    const float* v_b      = (const float*)d_in[7];
    const float* w_ih     = (const float*)d_in[8];
    const float* w_hh     = (const float*)d_in[9];
    const float* b_ih     = (const float*)d_in[10];
    const float* b_hh     = (const float*)d_in[11];
    const float* ln_in_g  = (const float*)d_in[12];
    const float* ln_in_b  = (const float*)d_in[13];
    const float* ln_s_g   = (const float*)d_in[14];
    const float* ln_s_b   = (const float*)d_in[15];
    const float* ln_p_g   = (const float*)d_in[16];
    const float* ln_p_b   = (const float*)d_in[17];
    const float* mlp1_w   = (const float*)d_in[18];
    const float* mlp1_b   = (const float*)d_in[19];
    const float* mlp2_w   = (const float*)d_in[20];
    const float* mlp2_b   = (const float*)d_in[21];
    const float* mlp3_w   = (const float*)d_in[22];
    const float* mlp3_b   = (const float*)d_in[23];
    const float* mlp4_w   = (const float*)d_in[24];
    const float* mlp4_b   = (const float*)d_in[25];
    float* out0 = (float*)d_out;                 // updates [32,8,512]
    float* out1 = (float*)d_out + Bb * NS * Dd;  // s [32,8,256]

    char* wp = (char*)d_ws;
    auto alloc = [&](size_t bytes) -> void* {
        void* p = (void*)wp;
        wp += (bytes + 255) & ~(size_t)255;
        return p;
    };
    const size_t MR = (size_t)Bb * Nn;  // 65536
    _Float16* Apack = (_Float16*)alloc(MR * 512 * 2);              // 67 MB
    _Float16* Bih   = (_Float16*)alloc((size_t)1536 * 1024 * 2);
    _Float16* Bhh   = (_Float16*)alloc((size_t)1536 * 1024 * 2);
    _Float16* Bm1   = (_Float16*)alloc((size_t)1024 * 1024 * 2);
    _Float16* Bm2   = (_Float16*)alloc((size_t)1024 * 2048 * 2);
    _Float16* Bm3   = (_Float16*)alloc((size_t)512 * 2048 * 2);
    _Float16* Bm4   = (_Float16*)alloc((size_t)256 * 1024 * 2);
    _Float16* Bvd   = (_Float16*)alloc((size_t)512 * 1024 * 2);    // v_w dup'd
    _Float16* BkT   = (_Float16*)alloc((size_t)512 * 512 * 2);     // k_w^T fp16
    float* slots    = (float*)alloc((size_t)Bb * NS * Dd * 4);
    _Float16* qh    = (_Float16*)alloc((size_t)Bb * NS * Dd * 2);
    float* cvec     = (float*)alloc((size_t)Bb * NS * 4);
    _Float16* Qk    = (_Float16*)alloc((size_t)256 * 1024 * 2);    // qk hi|lo
    float* rawp     = (float*)alloc((size_t)CHUNKS * Bb * NS * Dd * 4);  // 8 MB
    float* sumsp    = (float*)alloc((size_t)CHUNKS * Bb * NS * 4);
    _Float16* Whl   = (_Float16*)alloc((size_t)256 * 1024 * 2);    // W hi|lo
    float* ubuf     = (float*)alloc((size_t)Bb * NS * Dd * 4);
    float* gi       = (float*)alloc((size_t)Bb * NS * 1536 * 4);
    float* gh       = (float*)alloc((size_t)Bb * NS * 1536 * 4);
    _Float16* A2    = (_Float16*)alloc((size_t)512 * 1024 * 2);
    _Float16* P1    = (_Float16*)alloc((size_t)256 * 1024 * 2);
    _Float16* P2    = (_Float16*)alloc((size_t)256 * 2048 * 2);
    _Float16* P3    = (_Float16*)alloc((size_t)256 * 2048 * 2);
    _Float16* P4    = (_Float16*)alloc((size_t)256 * 1024 * 2);

    // ---- prep ----
    megapack_kernel<<<15872, 256, 0, stream>>>(
        w_ih, w_hh, mlp1_w, mlp2_w, mlp3_w, mlp4_w, v_w,
        Bih, Bhh, Bm1, Bm2, Bm3, Bm4, Bvd);
    kwt_kernel<<<dim3(8, 8), 256, 0, stream>>>(k_w, BkT);
    pack_ln_single_kernel<<<MR / 4, 256, 0, stream>>>(inputs, ln_in_g, ln_in_b, Apack);
    slots_init_kernel<<<64, 256, 0, stream>>>(noise, mu, lsig, slots, A2,
                                              ln_s_g, ln_s_b, qh, k_b, cvec);

    for (int it = 0; it < ITERS; ++it) {
        // qk = qh @ k_w  (hi|lo packed, no bias)
        hgemm64_kernel<0, 1, 0><<<dim3(8, 4), 256, 0, stream>>>(
            qh, BkT, nullptr, nullptr, Qk, 512, 512, 512);
        attn_kernel<<<dim3(CHUNKS, Bb), 256, 0, stream>>>(Apack, Qk, cvec, rawp, sumsp);
        finalize_kernel<<<512, 256, 0, stream>>>(rawp, sumsp, Whl);
        ugemm_kernel<<<dim3(8, 4), 256, 0, stream>>>(Whl, Bvd, v_b, ubuf, out0, A2);
        gru_gemm_kernel<<<dim3(24, 8), 256, 0, stream>>>(A2, Bih, Bhh, b_ih, b_hh, gi, gh);
        gru_elem_kernel<<<64, 256, 0, stream>>>(gi, gh, ubuf, slots, A2,
                                                ln_s_g, ln_s_b, qh, k_b, cvec,
                                                ln_p_g, ln_p_b, P1, it == ITERS - 1 ? 1 : 0);
    }

    // ---- output MLP ----
    hgemm64_kernel<1, 1, 1><<<dim3(16, 4), 256, 0, stream>>>(P1, Bm1, mlp1_b, nullptr, P2, 1024, 1024, 1024);
    hgemm64_kernel<1, 1, 1><<<dim3(16, 4), 256, 0, stream>>>(P2, Bm2, mlp2_b, nullptr, P3, 2048, 1024, 1024);
    hgemm64_kernel<1, 1, 1><<<dim3(8, 4), 256, 0, stream>>>(P3, Bm3, mlp3_b, nullptr, P4, 2048, 512, 512);
    hgemm64_kernel<0, 0, 1><<<dim3(4, 4), 256, 0, stream>>>(P4, Bm4, mlp4_b, out1, nullptr, 1024, 256, 256);
}